// Round 1
// baseline (1352.021 us; speedup 1.0000x reference)
//
#include <hip/hip_runtime.h>
#include <math.h>

// Problem constants
#define Hdim 1152
#define NHd  16
#define HDd  72
#define Bd   16
#define Sd   729
#define Ntok (Bd*Sd)      // 11664
#define BHd  (Bd*NHd)     // 256
#define VROW 736          // padded k-stride for transposed V (8B-aligned rows)
#define SCALE_F 0.117851130197757934f  // 72^-0.5

// scalar slots in ws
#define SL_X 0
#define SL_WQ 1
#define SL_WK 2
#define SL_WV 3
#define SL_WO 4
#define SL_Q 5
#define SL_K 6
#define SL_V 7
#define SL_LOGIT 8
#define SL_LMIN 9
#define SL_O 10

typedef short short8 __attribute__((ext_vector_type(8)));
typedef float f32x4 __attribute__((ext_vector_type(4)));

static __device__ __forceinline__ unsigned short f2bf(float f) {
  unsigned b = __float_as_uint(f);
  return (unsigned short)((b + 0x7FFFu + ((b >> 16) & 1u)) >> 16);  // RNE
}
static __device__ __forceinline__ float bf2f(unsigned short u) {
  return __uint_as_float(((unsigned)u) << 16);
}
static __device__ __forceinline__ void atomicMaxF(float* p, float v) {
  atomicMax((unsigned int*)p, __float_as_uint(v));   // v >= 0 only
}
static __device__ __forceinline__ void atomicMinF(float* p, float v) {
  atomicMin((unsigned int*)p, __float_as_uint(v));   // v > 0 only
}
static __device__ __forceinline__ float qscale(float mx, float qmax) {
  return fmaxf(mx, 1e-8f) / qmax;   // matches reference op order
}

// ---------------- init ----------------
__global__ void k_init(float* slots) {
  int i = threadIdx.x;
  if (i < 32) slots[i] = (i == SL_LMIN) ? __builtin_inff() : 0.0f;
}

// ---------------- abs-max over X and the 4 weights ----------------
__launch_bounds__(256)
__global__ void k_absmax(const float* __restrict__ X, const float* __restrict__ W0,
                         const float* __restrict__ W1, const float* __restrict__ W2,
                         const float* __restrict__ W3, float* slots) {
  int seg = blockIdx.y;
  const float* p; long n; int slot;
  if (seg == 0) { p = X; n = (long)Ntok * Hdim; slot = SL_X; }
  else {
    const float* ws4[4] = {W0, W1, W2, W3};
    p = ws4[seg - 1]; n = (long)Hdim * Hdim; slot = SL_WQ + seg - 1;
  }
  long n4 = n >> 2;
  const float4* p4 = (const float4*)p;
  float m = 0.f;
  for (long i = (long)blockIdx.x * blockDim.x + threadIdx.x; i < n4;
       i += (long)gridDim.x * blockDim.x) {
    float4 v = p4[i];
    m = fmaxf(m, fmaxf(fmaxf(fabsf(v.x), fabsf(v.y)), fmaxf(fabsf(v.z), fabsf(v.w))));
  }
  for (int off = 32; off; off >>= 1) m = fmaxf(m, __shfl_xor(m, off, 64));
  __shared__ float red[4];
  if ((threadIdx.x & 63) == 0) red[threadIdx.x >> 6] = m;
  __syncthreads();
  if (threadIdx.x == 0)
    atomicMaxF(&slots[slot], fmaxf(fmaxf(red[0], red[1]), fmaxf(red[2], red[3])));
}

// ---------------- 8-bit fake-quant: f32 -> integer-valued bf16 ----------------
__launch_bounds__(256)
__global__ void k_quant8(const float* __restrict__ in, unsigned short* __restrict__ out,
                         long n, const float* __restrict__ slots, int slot) {
  float s = qscale(slots[slot], 127.0f);
  long n4 = n >> 2;
  const float4* in4 = (const float4*)in;
  ushort4* out4 = (ushort4*)out;
  for (long i = (long)blockIdx.x * blockDim.x + threadIdx.x; i < n4;
       i += (long)gridDim.x * blockDim.x) {
    float4 v = in4[i];
    ushort4 o;
    o.x = f2bf(fminf(fmaxf(rintf(v.x / s), -128.f), 127.f));
    o.y = f2bf(fminf(fmaxf(rintf(v.y / s), -128.f), 127.f));
    o.z = f2bf(fminf(fmaxf(rintf(v.z / s), -128.f), 127.f));
    o.w = f2bf(fminf(fmaxf(rintf(v.w / s), -128.f), 127.f));
    out4[i] = o;
  }
}

// ---------------- GEMM: C = alpha * (A @ B^T) + bias ; A:(M,K) B:(N,K) bf16-int ----
#define GBM 128
#define GBN 64
#define GBK 32
__launch_bounds__(256)
__global__ void k_gemm(const unsigned short* __restrict__ A,
                       const unsigned short* __restrict__ Bm,
                       const float* __restrict__ bias,
                       float* __restrict__ C,
                       float* slots, int slotA, int slotB, int slotOut) {
  __shared__ unsigned short As[GBM][40];  // pad 32->40 (80B rows, 16B aligned, ~2-way banks)
  __shared__ unsigned short Bs[GBN][40];
  __shared__ float red[4];
  int tid = threadIdx.x, lane = tid & 63, wid = tid >> 6;
  int wm = wid >> 1, wn = wid & 1;
  int l15 = lane & 15, l4 = lane >> 4;
  int bM = blockIdx.x, bN = blockIdx.y;
  f32x4 acc[4][2];
  for (int rf = 0; rf < 4; ++rf)
    for (int cf = 0; cf < 2; ++cf) acc[rf][cf] = f32x4{0.f, 0.f, 0.f, 0.f};
  for (int kt = 0; kt < Hdim / GBK; ++kt) {
    int kb = kt * GBK;
    for (int idx = tid; idx < GBM * 8; idx += 256) {
      int r = idx >> 3, c = idx & 7;
      int gr = bM * GBM + r; if (gr > Ntok - 1) gr = Ntok - 1;
      *(ushort4*)&As[r][c * 4] = *(const ushort4*)&A[(long)gr * Hdim + kb + c * 4];
    }
    for (int idx = tid; idx < GBN * 8; idx += 256) {
      int r = idx >> 3, c = idx & 7;
      int gc = bN * GBN + r;
      *(ushort4*)&Bs[r][c * 4] = *(const ushort4*)&Bm[(long)gc * Hdim + kb + c * 4];
    }
    __syncthreads();
    short8 af[4], bf[2];
    for (int rf = 0; rf < 4; ++rf) af[rf] = *(const short8*)&As[wm * 64 + rf * 16 + l15][l4 * 8];
    for (int cf = 0; cf < 2; ++cf) bf[cf] = *(const short8*)&Bs[wn * 32 + cf * 16 + l15][l4 * 8];
    for (int rf = 0; rf < 4; ++rf)
      for (int cf = 0; cf < 2; ++cf)
        acc[rf][cf] = __builtin_amdgcn_mfma_f32_16x16x32_bf16(af[rf], bf[cf], acc[rf][cf], 0, 0, 0);
    __syncthreads();
  }
  float alpha = qscale(slots[slotA], 127.f) * qscale(slots[slotB], 127.f);
  float lmax = 0.f;
  for (int rf = 0; rf < 4; ++rf)
    for (int cf = 0; cf < 2; ++cf)
      for (int j = 0; j < 4; ++j) {
        int row = bM * GBM + wm * 64 + rf * 16 + l4 * 4 + j;
        int col = bN * GBN + wn * 32 + cf * 16 + l15;
        if (row < Ntok) {
          float v = acc[rf][cf][j] * alpha + bias[col];
          C[(long)row * Hdim + col] = v;
          lmax = fmaxf(lmax, fabsf(v));
        }
      }
  if (slotOut >= 0) {
    for (int off = 32; off; off >>= 1) lmax = fmaxf(lmax, __shfl_xor(lmax, off, 64));
    if ((tid & 63) == 0) red[wid] = lmax;
    __syncthreads();
    if (tid == 0)
      atomicMaxF(&slots[slotOut], fmaxf(fmaxf(red[0], red[1]), fmaxf(red[2], red[3])));
  }
}

// ---------------- V: (token,H) f32 -> per-head transposed hi/lo bf16 [bh][d][VROW] ----
__launch_bounds__(256)
__global__ void k_vsplit(const float* __restrict__ V, unsigned short* __restrict__ Vh,
                         unsigned short* __restrict__ Vl) {
  int bh = blockIdx.y, st = blockIdx.x;
  int b = bh >> 4, h = bh & 15;
  int s0 = st * 128;
  __shared__ float T[128][73];
  int tid = threadIdx.x;
  for (int idx = tid; idx < 128 * 18; idx += 256) {
    int r = idx / 18, c = idx % 18;
    int s = s0 + r;
    float4 v = make_float4(0.f, 0.f, 0.f, 0.f);
    if (s < Sd) v = *(const float4*)&V[((long)(b * Sd + s)) * Hdim + h * HDd + c * 4];
    T[r][c * 4 + 0] = v.x; T[r][c * 4 + 1] = v.y; T[r][c * 4 + 2] = v.z; T[r][c * 4 + 3] = v.w;
  }
  __syncthreads();
  for (int idx = tid; idx < HDd * 32; idx += 256) {
    int d = idx / 32, sc = idx % 32;
    int sl = sc * 4;
    int s = s0 + sl;
    long obase = ((long)(bh * HDd + d)) * VROW + s;
    if (s + 3 < Sd) {
      ushort4 hh, ll; float f;
      f = T[sl + 0][d]; hh.x = f2bf(f); ll.x = f2bf(f - bf2f(hh.x));
      f = T[sl + 1][d]; hh.y = f2bf(f); ll.y = f2bf(f - bf2f(hh.y));
      f = T[sl + 2][d]; hh.z = f2bf(f); ll.z = f2bf(f - bf2f(hh.z));
      f = T[sl + 3][d]; hh.w = f2bf(f); ll.w = f2bf(f - bf2f(hh.w));
      *(ushort4*)&Vh[obase] = hh; *(ushort4*)&Vl[obase] = ll;
    } else {
      for (int j = 0; j < 4; ++j) {
        int ss = s + j;
        if (ss < VROW) {
          float f = (ss < Sd) ? T[sl + j][d] : 0.f;
          unsigned short hb = f2bf(f);
          unsigned short lb = f2bf(f - bf2f(hb));
          Vh[obase + j] = hb; Vl[obase + j] = lb;
        }
      }
    }
  }
}

// ---------------- shared attn staging ----------------
static __device__ __forceinline__ void stage_tile(unsigned short (*dst)[104],
                                                  const unsigned short* __restrict__ src,
                                                  int b, int h, int s0, int tid) {
  for (int idx = tid; idx < 64 * 18; idx += 256) {
    int r = idx / 18, c = idx % 18;
    int s = s0 + r; if (s > Sd - 1) s = Sd - 1;
    *(ushort4*)&dst[r][c * 4] = *(const ushort4*)&src[((long)(b * Sd + s)) * Hdim + h * HDd + c * 4];
  }
  for (int idx = tid; idx < 64 * 6; idx += 256) {
    int r = idx / 6, c = idx % 6;
    *(ushort4*)&dst[r][72 + c * 4] = make_ushort4(0, 0, 0, 0);  // zero cols 72..95
  }
}

// ---------------- attn pass A: global max |logit| ----------------
__launch_bounds__(256)
__global__ void k_attnA(const unsigned short* __restrict__ Qq,
                        const unsigned short* __restrict__ Kq, float* slots) {
  int qt = blockIdx.x, bh = blockIdx.y;
  int b = bh >> 4, h = bh & 15;
  int tid = threadIdx.x, lane = tid & 63, w = tid >> 6;
  int l15 = lane & 15, l4 = lane >> 4;
  __shared__ unsigned short Qs[64][104];
  __shared__ unsigned short Ks[64][104];
  __shared__ float red[4];
  stage_tile(Qs, Qq, b, h, qt * 64, tid);
  __syncthreads();
  short8 qf[3];
  for (int c = 0; c < 3; ++c) qf[c] = *(const short8*)&Qs[w * 16 + l15][l4 * 8 + c * 32];
  float mx = 0.f;
  for (int kt = 0; kt < 12; ++kt) {
    __syncthreads();
    stage_tile(Ks, Kq, b, h, kt * 64, tid);
    __syncthreads();
    for (int cf = 0; cf < 4; ++cf) {
      f32x4 a = f32x4{0.f, 0.f, 0.f, 0.f};
      for (int c = 0; c < 3; ++c) {
        short8 kf = *(const short8*)&Ks[cf * 16 + l15][l4 * 8 + c * 32];
        a = __builtin_amdgcn_mfma_f32_16x16x32_bf16(qf[c], kf, a, 0, 0, 0);
      }
      int kcol = kt * 64 + cf * 16 + l15;
      if (kcol < Sd)
        for (int j = 0; j < 4; ++j) {
          int qrow = qt * 64 + w * 16 + l4 * 4 + j;
          if (qrow < Sd) mx = fmaxf(mx, fabsf(a[j]));
        }
    }
  }
  mx *= qscale(slots[SL_Q], 127.f) * qscale(slots[SL_K], 127.f);
  for (int off = 32; off; off >>= 1) mx = fmaxf(mx, __shfl_xor(mx, off, 64));
  if ((tid & 63) == 0) red[w] = mx;
  __syncthreads();
  if (tid == 0)
    atomicMaxF(&slots[SL_LOGIT], fmaxf(fmaxf(red[0], red[1]), fmaxf(red[2], red[3])));
}

// ---------------- attn pass B: per-row m,l ; global min l ----------------
__launch_bounds__(256)
__global__ void k_attnB(const unsigned short* __restrict__ Qq,
                        const unsigned short* __restrict__ Kq, float* slots,
                        float* __restrict__ m_arr, float* __restrict__ l_arr) {
  int qt = blockIdx.x, bh = blockIdx.y;
  int b = bh >> 4, h = bh & 15;
  int tid = threadIdx.x, lane = tid & 63, w = tid >> 6;
  int l15 = lane & 15, l4 = lane >> 4;
  __shared__ unsigned short Qs[64][104];
  __shared__ unsigned short Ks[64][104];
  __shared__ float red[4];
  stage_tile(Qs, Qq, b, h, qt * 64, tid);
  __syncthreads();
  short8 qf[3];
  for (int c = 0; c < 3; ++c) qf[c] = *(const short8*)&Qs[w * 16 + l15][l4 * 8 + c * 32];
  float s16 = qscale(slots[SL_LOGIT], 32767.f);
  float inv_s16 = 1.0f / s16;
  float sqk = qscale(slots[SL_Q], 127.f) * qscale(slots[SL_K], 127.f);
  float m_run[4] = {-__builtin_inff(), -__builtin_inff(), -__builtin_inff(), -__builtin_inff()};
  float l_run[4] = {0.f, 0.f, 0.f, 0.f};
  for (int kt = 0; kt < 12; ++kt) {
    __syncthreads();
    stage_tile(Ks, Kq, b, h, kt * 64, tid);
    __syncthreads();
    float zv[4][4];
    for (int cf = 0; cf < 4; ++cf) {
      f32x4 a = f32x4{0.f, 0.f, 0.f, 0.f};
      for (int c = 0; c < 3; ++c) {
        short8 kf = *(const short8*)&Ks[cf * 16 + l15][l4 * 8 + c * 32];
        a = __builtin_amdgcn_mfma_f32_16x16x32_bf16(qf[c], kf, a, 0, 0, 0);
      }
      int kcol = kt * 64 + cf * 16 + l15;
      bool vk = kcol < Sd;
      for (int j = 0; j < 4; ++j) {
        float t = a[j] * sqk;
        float n = fminf(fmaxf(rintf(t * inv_s16), -32768.f), 32767.f);
        float z = (n * s16) * SCALE_F;            // bit-match reference op order
        zv[cf][j] = vk ? z : -__builtin_inff();
      }
    }
    for (int j = 0; j < 4; ++j) {
      float mt = fmaxf(fmaxf(zv[0][j], zv[1][j]), fmaxf(zv[2][j], zv[3][j]));
      mt = fmaxf(mt, __shfl_xor(mt, 1, 64));
      mt = fmaxf(mt, __shfl_xor(mt, 2, 64));
      mt = fmaxf(mt, __shfl_xor(mt, 4, 64));
      mt = fmaxf(mt, __shfl_xor(mt, 8, 64));
      float mn = fmaxf(m_run[j], mt);
      float se = expf(zv[0][j] - mn) + expf(zv[1][j] - mn) +
                 expf(zv[2][j] - mn) + expf(zv[3][j] - mn);
      se += __shfl_xor(se, 1, 64);
      se += __shfl_xor(se, 2, 64);
      se += __shfl_xor(se, 4, 64);
      se += __shfl_xor(se, 8, 64);
      l_run[j] = l_run[j] * expf(m_run[j] - mn) + se;
      m_run[j] = mn;
    }
  }
  float lmin = __builtin_inff();
  for (int j = 0; j < 4; ++j) {
    int qrow = qt * 64 + w * 16 + l4 * 4 + j;
    if (qrow < Sd) {
      if (l15 == 0) { m_arr[bh * Sd + qrow] = m_run[j]; l_arr[bh * Sd + qrow] = l_run[j]; }
      lmin = fminf(lmin, l_run[j]);
    }
  }
  for (int off = 32; off; off >>= 1) lmin = fminf(lmin, __shfl_xor(lmin, off, 64));
  if ((tid & 63) == 0) red[w] = lmin;
  __syncthreads();
  if (tid == 0)
    atomicMinF(&slots[SL_LMIN], fminf(fminf(red[0], red[1]), fminf(red[2], red[3])));
}

// ---------------- attn pass C: P quant (split) + P@V + max|O| ----------------
__launch_bounds__(256)
__global__ void k_attnC(const unsigned short* __restrict__ Qq,
                        const unsigned short* __restrict__ Kq,
                        const unsigned short* __restrict__ Vh,
                        const unsigned short* __restrict__ Vl,
                        const float* __restrict__ m_arr, const float* __restrict__ l_arr,
                        float* slots, float* __restrict__ O) {
  int qt = blockIdx.x, bh = blockIdx.y;
  int b = bh >> 4, h = bh & 15;
  int tid = threadIdx.x, lane = tid & 63, w = tid >> 6;
  int l15 = lane & 15, l4 = lane >> 4;
  __shared__ unsigned short Qs[64][104];
  __shared__ unsigned short Ks[64][104];
  __shared__ unsigned short Vhs[80][72];
  __shared__ unsigned short Vls[80][72];
  __shared__ unsigned short Ph[4][16][72];
  __shared__ unsigned short Pl[4][16][72];
  __shared__ float red[4];
  stage_tile(Qs, Qq, b, h, qt * 64, tid);
  __syncthreads();
  short8 qf[3];
  for (int c = 0; c < 3; ++c) qf[c] = *(const short8*)&Qs[w * 16 + l15][l4 * 8 + c * 32];
  float s16 = qscale(slots[SL_LOGIT], 32767.f);
  float inv_s16 = 1.0f / s16;
  float sqk = qscale(slots[SL_Q], 127.f) * qscale(slots[SL_K], 127.f);
  float pmax = 1.0f / slots[SL_LMIN];
  float sp = fmaxf(pmax, 1e-8f) / 32767.0f;
  float inv_sp = 1.0f / sp;
  float m4[4], invl[4];
  for (int j = 0; j < 4; ++j) {
    int qrow = qt * 64 + w * 16 + l4 * 4 + j;
    if (qrow < Sd) { m4[j] = m_arr[bh * Sd + qrow]; invl[j] = 1.0f / l_arr[bh * Sd + qrow]; }
    else { m4[j] = 0.f; invl[j] = 1.f; }
  }
  f32x4 aH[5], aL[5];
  for (int i = 0; i < 5; ++i) { aH[i] = f32x4{0.f,0.f,0.f,0.f}; aL[i] = f32x4{0.f,0.f,0.f,0.f}; }
  long vbase = (long)bh * HDd * VROW;
  for (int kt = 0; kt < 12; ++kt) {
    __syncthreads();
    stage_tile(Ks, Kq, b, h, kt * 64, tid);
    for (int idx = tid; idx < 72 * 16; idx += 256) {
      int d = idx / 16, c = idx % 16;
      int ks = kt * 64 + c * 4; if (ks > 732) ks = 732;  // pad zone holds zeros
      *(ushort4*)&Vhs[d][c * 4] = *(const ushort4*)&Vh[vbase + (long)d * VROW + ks];
      *(ushort4*)&Vls[d][c * 4] = *(const ushort4*)&Vl[vbase + (long)d * VROW + ks];
    }
    for (int idx = tid; idx < 8 * 16; idx += 256) {
      int d = 72 + idx / 16, c = idx % 16;
      *(ushort4*)&Vhs[d][c * 4] = make_ushort4(0, 0, 0, 0);
      *(ushort4*)&Vls[d][c * 4] = make_ushort4(0, 0, 0, 0);
    }
    __syncthreads();
    for (int cf = 0; cf < 4; ++cf) {
      f32x4 a = f32x4{0.f, 0.f, 0.f, 0.f};
      for (int c = 0; c < 3; ++c) {
        short8 kf = *(const short8*)&Ks[cf * 16 + l15][l4 * 8 + c * 32];
        a = __builtin_amdgcn_mfma_f32_16x16x32_bf16(qf[c], kf, a, 0, 0, 0);
      }
      int kcol = kt * 64 + cf * 16 + l15;
      bool vk = kcol < Sd;
      for (int j = 0; j < 4; ++j) {
        float t = a[j] * sqk;
        float n = fminf(fmaxf(rintf(t * inv_s16), -32768.f), 32767.f);
        float z = (n * s16) * SCALE_F;
        float p = expf(z - m4[j]) * invl[j];
        float nn = fminf(rintf(p * inv_sp), 32767.f);
        int ni = vk ? (int)nn : 0;
        Ph[w][l4 * 4 + j][cf * 16 + l15] = f2bf((float)(ni >> 8));
        Pl[w][l4 * 4 + j][cf * 16 + l15] = f2bf((float)(ni & 255));
      }
    }
    // wave-private P tiles: same-wave DS ordering; compiler inserts lgkmcnt waits
    short8 pfh[2], pfl[2];
    for (int c2 = 0; c2 < 2; ++c2) {
      pfh[c2] = *(const short8*)&Ph[w][l15][l4 * 8 + c2 * 32];
      pfl[c2] = *(const short8*)&Pl[w][l15][l4 * 8 + c2 * 32];
    }
    for (int cf2 = 0; cf2 < 5; ++cf2)
      for (int c2 = 0; c2 < 2; ++c2) {
        short8 vh = *(const short8*)&Vhs[cf2 * 16 + l15][l4 * 8 + c2 * 32];
        short8 vl = *(const short8*)&Vls[cf2 * 16 + l15][l4 * 8 + c2 * 32];
        aH[cf2] = __builtin_amdgcn_mfma_f32_16x16x32_bf16(pfh[c2], vh, aH[cf2], 0, 0, 0);
        aH[cf2] = __builtin_amdgcn_mfma_f32_16x16x32_bf16(pfh[c2], vl, aH[cf2], 0, 0, 0);
        aL[cf2] = __builtin_amdgcn_mfma_f32_16x16x32_bf16(pfl[c2], vh, aL[cf2], 0, 0, 0);
        aL[cf2] = __builtin_amdgcn_mfma_f32_16x16x32_bf16(pfl[c2], vl, aL[cf2], 0, 0, 0);
      }
  }
  float lmax = 0.f;
  for (int cf2 = 0; cf2 < 5; ++cf2) {
    int d = cf2 * 16 + l15;
    if (d < HDd)
      for (int j = 0; j < 4; ++j) {
        int qrow = qt * 64 + w * 16 + l4 * 4 + j;
        if (qrow < Sd) {
          float v = sp * (256.0f * aH[cf2][j] + aL[cf2][j]);
          O[((long)(b * Sd + qrow)) * Hdim + h * HDd + d] = v;
          lmax = fmaxf(lmax, fabsf(v));
        }
      }
  }
  for (int off = 32; off; off >>= 1) lmax = fmaxf(lmax, __shfl_xor(lmax, off, 64));
  if ((tid & 63) == 0) red[w] = lmax;
  __syncthreads();
  if (tid == 0)
    atomicMaxF(&slots[SL_O], fmaxf(fmaxf(red[0], red[1]), fmaxf(red[2], red[3])));
}

// ---------------- host ----------------
extern "C" void kernel_launch(void* const* d_in, const int* in_sizes, int n_in,
                              void* d_out, int out_size, void* d_ws, size_t ws_size,
                              hipStream_t stream) {
  const float* Xin = (const float*)d_in[0];
  const float* Wq = (const float*)d_in[1];
  const float* bq = (const float*)d_in[2];
  const float* Wk = (const float*)d_in[3];
  const float* bk = (const float*)d_in[4];
  const float* Wv = (const float*)d_in[5];
  const float* bv = (const float*)d_in[6];
  const float* Wo = (const float*)d_in[7];
  const float* bo = (const float*)d_in[8];
  float* out = (float*)d_out;
  char* ws = (char*)d_ws;

  size_t off = 0;
  auto alloc = [&](size_t bytes) {
    void* p = ws + off;
    off = (off + bytes + 255) & ~(size_t)255;
    return p;
  };
  float* slots = (float*)alloc(256);
  unsigned short* Xq  = (unsigned short*)alloc((size_t)Ntok * Hdim * 2);
  unsigned short* Wqq = (unsigned short*)alloc((size_t)Hdim * Hdim * 2);
  unsigned short* Wkq = (unsigned short*)alloc((size_t)Hdim * Hdim * 2);
  unsigned short* Wvq = (unsigned short*)alloc((size_t)Hdim * Hdim * 2);
  unsigned short* Woq = (unsigned short*)alloc((size_t)Hdim * Hdim * 2);
  float* Kf = (float*)alloc((size_t)Ntok * Hdim * 4);
  float* Vf = (float*)alloc((size_t)Ntok * Hdim * 4);
  unsigned short* Qq = (unsigned short*)alloc((size_t)Ntok * Hdim * 2);
  unsigned short* Kq = (unsigned short*)alloc((size_t)Ntok * Hdim * 2);
  unsigned short* Vth = (unsigned short*)alloc((size_t)BHd * HDd * VROW * 2);
  unsigned short* Vtl = (unsigned short*)alloc((size_t)BHd * HDd * VROW * 2);
  float* m_arr = (float*)alloc((size_t)BHd * Sd * 4);
  float* l_arr = (float*)alloc((size_t)BHd * Sd * 4);
  // aliases (lifetimes disjoint): Qf32 in d_out; O f32 over Kf; Oq over Vf
  float* Qf = out;
  float* Of = Kf;
  unsigned short* Oq = (unsigned short*)Vf;

  k_init<<<1, 64, 0, stream>>>(slots);
  k_absmax<<<dim3(256, 5), 256, 0, stream>>>(Xin, Wq, Wk, Wv, Wo, slots);
  k_quant8<<<1024, 256, 0, stream>>>(Xin, Xq, (long)Ntok * Hdim, slots, SL_X);
  k_quant8<<<512, 256, 0, stream>>>(Wq, Wqq, (long)Hdim * Hdim, slots, SL_WQ);
  k_quant8<<<512, 256, 0, stream>>>(Wk, Wkq, (long)Hdim * Hdim, slots, SL_WK);
  k_quant8<<<512, 256, 0, stream>>>(Wv, Wvq, (long)Hdim * Hdim, slots, SL_WV);
  k_quant8<<<512, 256, 0, stream>>>(Wo, Woq, (long)Hdim * Hdim, slots, SL_WO);

  dim3 ggrid(92, 18);
  k_gemm<<<ggrid, 256, 0, stream>>>(Xq, Wqq, bq, Qf, slots, SL_X, SL_WQ, SL_Q);
  k_gemm<<<ggrid, 256, 0, stream>>>(Xq, Wkq, bk, Kf, slots, SL_X, SL_WK, SL_K);
  k_gemm<<<ggrid, 256, 0, stream>>>(Xq, Wvq, bv, Vf, slots, SL_X, SL_WV, SL_V);

  k_quant8<<<1024, 256, 0, stream>>>(Qf, Qq, (long)Ntok * Hdim, slots, SL_Q);
  k_quant8<<<1024, 256, 0, stream>>>(Kf, Kq, (long)Ntok * Hdim, slots, SL_K);
  k_vsplit<<<dim3(6, 256), 256, 0, stream>>>(Vf, Vth, Vtl);

  dim3 agrid(12, 256);
  k_attnA<<<agrid, 256, 0, stream>>>(Qq, Kq, slots);
  k_attnB<<<agrid, 256, 0, stream>>>(Qq, Kq, slots, m_arr, l_arr);
  k_attnC<<<agrid, 256, 0, stream>>>(Qq, Kq, Vth, Vtl, m_arr, l_arr, slots, Of);

  k_quant8<<<1024, 256, 0, stream>>>(Of, Oq, (long)Ntok * Hdim, slots, SL_O);
  k_gemm<<<ggrid, 256, 0, stream>>>(Oq, Woq, bo, out, slots, SL_O, SL_WO, -1);
}

// Round 2
// 846.916 us; speedup vs baseline: 1.5964x; 1.5964x over previous
//
#include <hip/hip_runtime.h>
#include <math.h>

// Problem constants
#define Hdim 1152
#define NHd  16
#define HDd  72
#define Bd   16
#define Sd   729
#define Ntok (Bd*Sd)      // 11664
#define BHd  (Bd*NHd)     // 256
#define VROW 768          // padded k-stride for transposed V (covers 12*64, zeros >728)
#define SCALE_F 0.117851130197757934f  // 72^-0.5
#define LOG2E 1.44269504088896340736f

// scalar slots in ws
#define SL_X 0
#define SL_WQ 1
#define SL_WK 2
#define SL_WV 3
#define SL_WO 4
#define SL_Q 5
#define SL_K 6
#define SL_V 7
#define SL_LOGIT 8
#define SL_LMIN 9
#define SL_O 10

typedef short short8 __attribute__((ext_vector_type(8)));
typedef short short4v __attribute__((ext_vector_type(4)));
typedef float f32x4 __attribute__((ext_vector_type(4)));

static __device__ __forceinline__ unsigned short f2bf(float f) {
  unsigned b = __float_as_uint(f);
  return (unsigned short)((b + 0x7FFFu + ((b >> 16) & 1u)) >> 16);  // RNE
}
static __device__ __forceinline__ float bf2f(unsigned short u) {
  return __uint_as_float(((unsigned)u) << 16);
}
static __device__ __forceinline__ void atomicMaxF(float* p, float v) {
  atomicMax((unsigned int*)p, __float_as_uint(v));   // v >= 0 only
}
static __device__ __forceinline__ void atomicMinF(float* p, float v) {
  atomicMin((unsigned int*)p, __float_as_uint(v));   // v > 0 only
}
static __device__ __forceinline__ float qscale(float mx, float qmax) {
  return fmaxf(mx, 1e-8f) / qmax;
}
static __device__ __forceinline__ float fexp2(float x) {
  float r; asm("v_exp_f32 %0, %1" : "=v"(r) : "v"(x)); return r;
}
static __device__ __forceinline__ short4v pack4(unsigned a, unsigned b, unsigned c, unsigned d) {
  union { unsigned u[2]; short4v s; } t;
  t.u[0] = a | (b << 16);
  t.u[1] = c | (d << 16);
  return t.s;
}

#define MFMA32(a, b, c) __builtin_amdgcn_mfma_f32_16x16x32_bf16(a, b, c, 0, 0, 0)
#if __has_builtin(__builtin_amdgcn_mfma_f32_16x16x16bf16_1k)
#define MFMA16(a, b, c) __builtin_amdgcn_mfma_f32_16x16x16bf16_1k(a, b, c, 0, 0, 0)
#else
static __device__ __forceinline__ f32x4 MFMA16(short4v a, short4v b, f32x4 c) {
  asm("v_mfma_f32_16x16x16_bf16 %0, %1, %2, %0" : "+v"(c) : "v"(a), "v"(b));
  return c;
}
#endif

static __device__ __forceinline__ void gll16(const void* g, void* l) {
  __builtin_amdgcn_global_load_lds((const __attribute__((address_space(1))) void*)g,
                                   (__attribute__((address_space(3))) void*)l, 16, 0, 0);
}

// ---------------- init ----------------
__global__ void k_init(float* slots) {
  int i = threadIdx.x;
  if (i < 32) slots[i] = (i == SL_LMIN) ? __builtin_inff() : 0.0f;
}

// ---------------- abs-max over X and the 4 weights ----------------
__launch_bounds__(256)
__global__ void k_absmax(const float* __restrict__ X, const float* __restrict__ W0,
                         const float* __restrict__ W1, const float* __restrict__ W2,
                         const float* __restrict__ W3, float* slots) {
  int seg = blockIdx.y;
  const float* p; long n; int slot;
  if (seg == 0) { p = X; n = (long)Ntok * Hdim; slot = SL_X; }
  else {
    const float* ws4[4] = {W0, W1, W2, W3};
    p = ws4[seg - 1]; n = (long)Hdim * Hdim; slot = SL_WQ + seg - 1;
  }
  long n4 = n >> 2;
  const float4* p4 = (const float4*)p;
  float m = 0.f;
  for (long i = (long)blockIdx.x * blockDim.x + threadIdx.x; i < n4;
       i += (long)gridDim.x * blockDim.x) {
    float4 v = p4[i];
    m = fmaxf(m, fmaxf(fmaxf(fabsf(v.x), fabsf(v.y)), fmaxf(fabsf(v.z), fabsf(v.w))));
  }
  for (int off = 32; off; off >>= 1) m = fmaxf(m, __shfl_xor(m, off, 64));
  __shared__ float red[4];
  if ((threadIdx.x & 63) == 0) red[threadIdx.x >> 6] = m;
  __syncthreads();
  if (threadIdx.x == 0)
    atomicMaxF(&slots[slot], fmaxf(fmaxf(red[0], red[1]), fmaxf(red[2], red[3])));
}

// ---------------- 8-bit fake-quant: f32 -> integer-valued bf16 ----------------
__launch_bounds__(256)
__global__ void k_quant8(const float* __restrict__ in, unsigned short* __restrict__ out,
                         long n, const float* __restrict__ slots, int slot) {
  float s = qscale(slots[slot], 127.0f);
  long n4 = n >> 2;
  const float4* in4 = (const float4*)in;
  ushort4* out4 = (ushort4*)out;
  for (long i = (long)blockIdx.x * blockDim.x + threadIdx.x; i < n4;
       i += (long)gridDim.x * blockDim.x) {
    float4 v = in4[i];
    ushort4 o;
    o.x = f2bf(fminf(fmaxf(rintf(v.x / s), -128.f), 127.f));
    o.y = f2bf(fminf(fmaxf(rintf(v.y / s), -128.f), 127.f));
    o.z = f2bf(fminf(fmaxf(rintf(v.z / s), -128.f), 127.f));
    o.w = f2bf(fminf(fmaxf(rintf(v.w / s), -128.f), 127.f));
    out4[i] = o;
  }
}

// combined 4-weight quant (saves launches)
__launch_bounds__(256)
__global__ void k_quant8w(const float* __restrict__ W0, const float* __restrict__ W1,
                          const float* __restrict__ W2, const float* __restrict__ W3,
                          unsigned short* O0, unsigned short* O1,
                          unsigned short* O2, unsigned short* O3,
                          const float* __restrict__ slots) {
  int seg = blockIdx.y;
  const float* ws4[4] = {W0, W1, W2, W3};
  unsigned short* os4[4] = {O0, O1, O2, O3};
  const float* in = ws4[seg];
  unsigned short* out = os4[seg];
  float s = qscale(slots[SL_WQ + seg], 127.0f);
  long n4 = ((long)Hdim * Hdim) >> 2;
  const float4* in4 = (const float4*)in;
  ushort4* out4 = (ushort4*)out;
  for (long i = (long)blockIdx.x * blockDim.x + threadIdx.x; i < n4;
       i += (long)gridDim.x * blockDim.x) {
    float4 v = in4[i];
    ushort4 o;
    o.x = f2bf(fminf(fmaxf(rintf(v.x / s), -128.f), 127.f));
    o.y = f2bf(fminf(fmaxf(rintf(v.y / s), -128.f), 127.f));
    o.z = f2bf(fminf(fmaxf(rintf(v.z / s), -128.f), 127.f));
    o.w = f2bf(fminf(fmaxf(rintf(v.w / s), -128.f), 127.f));
    out4[i] = o;
  }
}

// ---------------- GEMM (m97 structure): C = alpha*(A@B^T) + bias ----------------
#define GBM 128
#define GBN 128
#define GBK 32
__launch_bounds__(256, 3)
__global__ void k_gemm(const unsigned short* __restrict__ A,
                       const unsigned short* __restrict__ Bm,
                       const float* __restrict__ bias,
                       float* __restrict__ C,
                       float* slots, int slotA, int slotB, int slotOut) {
  __shared__ unsigned short As[GBM][GBK];   // linear, gll-friendly, conflict-free reads
  __shared__ unsigned short Bs[GBN][GBK];
  __shared__ float red[4];
  int tid = threadIdx.x, lane = tid & 63, wid = tid >> 6;
  int wm = wid >> 1, wn = wid & 1;
  int l15 = lane & 15, l4 = lane >> 4;
  int bM = blockIdx.x, bN = blockIdx.y;
  f32x4 acc[4][4];
  for (int rf = 0; rf < 4; ++rf)
    for (int cf = 0; cf < 4; ++cf) acc[rf][cf] = f32x4{0.f, 0.f, 0.f, 0.f};

  int srow = lane >> 2, scol = (lane & 3) * 8;
  const unsigned short* pa = A + ((long)(bM * GBM + wid * 32) + srow) * Hdim + scol;
  const unsigned short* pb = Bm + ((long)(bN * GBN + wid * 32) + srow) * Hdim + scol;

  for (int kt = 0; kt < Hdim / GBK; ++kt) {
    int kb = kt * GBK;
    __syncthreads();   // prev tile's reads done
    gll16(pa + kb, &As[wid * 32][0]);
    gll16(pa + kb + 16 * Hdim, &As[wid * 32 + 16][0]);
    gll16(pb + kb, &Bs[wid * 32][0]);
    gll16(pb + kb + 16 * Hdim, &Bs[wid * 32 + 16][0]);
    __syncthreads();   // gll complete (vmcnt drained before barrier)
    short8 af[4], bf[4];
#pragma unroll
    for (int rf = 0; rf < 4; ++rf) af[rf] = *(const short8*)&As[wm * 64 + rf * 16 + l15][l4 * 8];
#pragma unroll
    for (int cf = 0; cf < 4; ++cf) bf[cf] = *(const short8*)&Bs[wn * 64 + cf * 16 + l15][l4 * 8];
#pragma unroll
    for (int rf = 0; rf < 4; ++rf)
#pragma unroll
      for (int cf = 0; cf < 4; ++cf)
        acc[rf][cf] = MFMA32(af[rf], bf[cf], acc[rf][cf]);
  }
  float alpha = qscale(slots[slotA], 127.f) * qscale(slots[slotB], 127.f);
  float lmax = 0.f;
#pragma unroll
  for (int cf = 0; cf < 4; ++cf) {
    int col = bN * GBN + wn * 64 + cf * 16 + l15;
    float bv = bias[col];
#pragma unroll
    for (int rf = 0; rf < 4; ++rf)
#pragma unroll
      for (int j = 0; j < 4; ++j) {
        int row = bM * GBM + wm * 64 + rf * 16 + l4 * 4 + j;
        if (row < Ntok) {
          float v = acc[rf][cf][j] * alpha + bv;
          C[(long)row * Hdim + col] = v;
          lmax = fmaxf(lmax, fabsf(v));
        }
      }
  }
  if (slotOut >= 0) {
    for (int off = 32; off; off >>= 1) lmax = fmaxf(lmax, __shfl_xor(lmax, off, 64));
    if ((tid & 63) == 0) red[wid] = lmax;
    __syncthreads();
    if (tid == 0)
      atomicMaxF(&slots[slotOut], fmaxf(fmaxf(red[0], red[1]), fmaxf(red[2], red[3])));
  }
}

// ---------------- V: (token,H) f32 -> per-head transposed hi/lo bf16 [bh][d][VROW] ----
__launch_bounds__(256)
__global__ void k_vsplit(const float* __restrict__ V, unsigned short* __restrict__ Vh,
                         unsigned short* __restrict__ Vl) {
  int bh = blockIdx.y, st = blockIdx.x;
  int b = bh >> 4, h = bh & 15;
  int s0 = st * 128;
  __shared__ float T[128][73];
  int tid = threadIdx.x;
  for (int idx = tid; idx < 128 * 18; idx += 256) {
    int r = idx / 18, c = idx % 18;
    int s = s0 + r;
    float4 v = make_float4(0.f, 0.f, 0.f, 0.f);
    if (s < Sd) v = *(const float4*)&V[((long)(b * Sd + s)) * Hdim + h * HDd + c * 4];
    T[r][c * 4 + 0] = v.x; T[r][c * 4 + 1] = v.y; T[r][c * 4 + 2] = v.z; T[r][c * 4 + 3] = v.w;
  }
  __syncthreads();
  for (int idx = tid; idx < HDd * 32; idx += 256) {
    int d = idx / 32, sc = idx % 32;
    int sl = sc * 4;
    int s = s0 + sl;
    long obase = ((long)(bh * HDd + d)) * VROW + s;
    if (s + 3 < Sd) {
      ushort4 hh, ll; float f;
      f = T[sl + 0][d]; hh.x = f2bf(f); ll.x = f2bf(f - bf2f(hh.x));
      f = T[sl + 1][d]; hh.y = f2bf(f); ll.y = f2bf(f - bf2f(hh.y));
      f = T[sl + 2][d]; hh.z = f2bf(f); ll.z = f2bf(f - bf2f(hh.z));
      f = T[sl + 3][d]; hh.w = f2bf(f); ll.w = f2bf(f - bf2f(hh.w));
      *(ushort4*)&Vh[obase] = hh; *(ushort4*)&Vl[obase] = ll;
    } else {
      for (int j = 0; j < 4; ++j) {
        int ss = s + j;
        if (ss < VROW) {
          float f = (ss < Sd) ? T[sl + j][d] : 0.f;
          unsigned short hb = f2bf(f);
          unsigned short lb = f2bf(f - bf2f(hb));
          Vh[obase + j] = hb; Vl[obase + j] = lb;
        }
      }
    }
  }
}

// ---------------- shared attn staging (K tile, cols 0..72 only) ----------------
static __device__ __forceinline__ void stageK(unsigned short (*Ks)[104],
                                              const unsigned short* __restrict__ Kq,
                                              int b, int h, int s0, int tid) {
  const unsigned short* base = Kq + (long)b * Sd * Hdim + h * HDd;
  for (int idx = tid; idx < 64 * 9; idx += 256) {
    int r = idx / 9, c = idx - r * 9;
    int s = s0 + r; if (s > Sd - 1) s = Sd - 1;
    *(short8*)&Ks[r][c * 8] = *(const short8*)&base[(long)s * Hdim + c * 8];
  }
}
static __device__ __forceinline__ void zeroKpad(unsigned short (*Ks)[104], int tid) {
  for (int idx = tid; idx < 64 * 3; idx += 256) {
    int r = idx / 3, c = idx - r * 3;
    *(short8*)&Ks[r][72 + c * 8] = (short8)0;
  }
}

// per-lane Q fragments straight from global (no LDS)
static __device__ __forceinline__ void loadQ(const unsigned short* __restrict__ Qq,
                                             int b, int h, int qc, int l4,
                                             short8& q0, short8& q1, short8& q2) {
  const unsigned short* qp = &Qq[((long)(b * Sd + qc)) * Hdim + h * HDd];
  q0 = *(const short8*)&qp[l4 * 8];
  q1 = *(const short8*)&qp[32 + l4 * 8];
  q2 = (short8)0;
  if (l4 == 0) q2 = *(const short8*)&qp[64];
}

// ---------------- attn pass A: global max |logit| ----------------
__launch_bounds__(256, 4)
__global__ void k_attnA(const unsigned short* __restrict__ Qq,
                        const unsigned short* __restrict__ Kq, float* slots) {
  __shared__ unsigned short Ks[64][104];
  __shared__ float red[4];
  int qt = blockIdx.x, bh = blockIdx.y, b = bh >> 4, h = bh & 15;
  int tid = threadIdx.x, lane = tid & 63, w = tid >> 6;
  int l15 = lane & 15, l4 = lane >> 4;
  zeroKpad(Ks, tid);
  int qrow = qt * 64 + w * 16 + l15;
  int qc = qrow > Sd - 1 ? Sd - 1 : qrow;
  short8 q0, q1, q2;
  loadQ(Qq, b, h, qc, l4, q0, q1, q2);
  float mx = 0.f;
#pragma unroll 1
  for (int kt = 0; kt < 12; ++kt) {
    __syncthreads();
    stageK(Ks, Kq, b, h, kt * 64, tid);
    __syncthreads();
#pragma unroll
    for (int cf = 0; cf < 4; ++cf) {
      const unsigned short* kp = &Ks[cf * 16 + l15][l4 * 8];
      f32x4 a = f32x4{0.f, 0.f, 0.f, 0.f};
      a = MFMA32(*(const short8*)&kp[0],  q0, a);
      a = MFMA32(*(const short8*)&kp[32], q1, a);
      a = MFMA32(*(const short8*)&kp[64], q2, a);
      mx = fmaxf(mx, fmaxf(fmaxf(fabsf(a[0]), fabsf(a[1])), fmaxf(fabsf(a[2]), fabsf(a[3]))));
    }
  }
  mx *= qscale(slots[SL_Q], 127.f) * qscale(slots[SL_K], 127.f);
  for (int off = 32; off; off >>= 1) mx = fmaxf(mx, __shfl_xor(mx, off, 64));
  if ((tid & 63) == 0) red[w] = mx;
  __syncthreads();
  if (tid == 0)
    atomicMaxF(&slots[SL_LOGIT], fmaxf(fmaxf(red[0], red[1]), fmaxf(red[2], red[3])));
}

// ---------------- attn pass B: per-row m (n-space), l ; global min l ----------------
__launch_bounds__(256, 4)
__global__ void k_attnB(const unsigned short* __restrict__ Qq,
                        const unsigned short* __restrict__ Kq, float* slots,
                        float* __restrict__ m_arr, float* __restrict__ l_arr) {
  __shared__ unsigned short Ks[64][104];
  __shared__ float red[4];
  int qt = blockIdx.x, bh = blockIdx.y, b = bh >> 4, h = bh & 15;
  int tid = threadIdx.x, lane = tid & 63, w = tid >> 6;
  int l15 = lane & 15, l4 = lane >> 4;
  zeroKpad(Ks, tid);
  int qrow = qt * 64 + w * 16 + l15;
  int qc = qrow > Sd - 1 ? Sd - 1 : qrow;
  short8 q0, q1, q2;
  loadQ(Qq, b, h, qc, l4, q0, q1, q2);
  float s16 = qscale(slots[SL_LOGIT], 32767.f);
  float sqk = qscale(slots[SL_Q], 127.f) * qscale(slots[SL_K], 127.f);
  float c0 = sqk / s16;                 // raw-dot -> n units
  float c1e = s16 * SCALE_F * LOG2E;    // n units -> log2 space
  float m_run = -3.0e38f, l_run = 0.f;
#pragma unroll 1
  for (int kt = 0; kt < 12; ++kt) {
    __syncthreads();
    stageK(Ks, Kq, b, h, kt * 64, tid);
    __syncthreads();
    float nv[16];
#pragma unroll
    for (int cf = 0; cf < 4; ++cf) {
      const unsigned short* kp = &Ks[cf * 16 + l15][l4 * 8];
      f32x4 a = f32x4{0.f, 0.f, 0.f, 0.f};
      a = MFMA32(*(const short8*)&kp[0],  q0, a);
      a = MFMA32(*(const short8*)&kp[32], q1, a);
      a = MFMA32(*(const short8*)&kp[64], q2, a);
#pragma unroll
      for (int j = 0; j < 4; ++j) nv[cf * 4 + j] = rintf(a[j] * c0);
    }
    if (kt == 11) {
#pragma unroll
      for (int cf = 0; cf < 4; ++cf)
#pragma unroll
        for (int j = 0; j < 4; ++j) {
          int kcol = 704 + cf * 16 + l4 * 4 + j;
          if (kcol > Sd - 1) nv[cf * 4 + j] = -3.0e30f;
        }
    }
    float mt = nv[0];
#pragma unroll
    for (int i = 1; i < 16; ++i) mt = fmaxf(mt, nv[i]);
    mt = fmaxf(mt, __shfl_xor(mt, 16, 64));
    mt = fmaxf(mt, __shfl_xor(mt, 32, 64));
    float mn = fmaxf(m_run, mt);
    float f = fexp2((m_run - mn) * c1e);
    float se = 0.f;
#pragma unroll
    for (int i = 0; i < 16; ++i) se += fexp2((nv[i] - mn) * c1e);
    se += __shfl_xor(se, 16, 64);
    se += __shfl_xor(se, 32, 64);
    l_run = l_run * f + se;
    m_run = mn;
  }
  if (l4 == 0 && qrow < Sd) {
    m_arr[bh * Sd + qrow] = m_run;      // n-space max
    l_arr[bh * Sd + qrow] = l_run;
  }
  float lmin = (qrow < Sd) ? l_run : 3.0e38f;
  for (int off = 32; off; off >>= 1) lmin = fminf(lmin, __shfl_xor(lmin, off, 64));
  if ((tid & 63) == 0) red[w] = lmin;
  __syncthreads();
  if (tid == 0)
    atomicMinF(&slots[SL_LMIN], fminf(fminf(red[0], red[1]), fminf(red[2], red[3])));
}

// ---------------- attn pass C: register-P quant + P@V + max|O| ----------------
__launch_bounds__(256, 4)
__global__ void k_attnC(const unsigned short* __restrict__ Qq,
                        const unsigned short* __restrict__ Kq,
                        const unsigned short* __restrict__ Vh,
                        const unsigned short* __restrict__ Vl,
                        const float* __restrict__ m_arr, const float* __restrict__ l_arr,
                        float* slots, float* __restrict__ O) {
  __shared__ unsigned short Ks[64][104];
  __shared__ unsigned short Vhs[80][80];   // stride 80: conflict-free b64 frag reads
  __shared__ unsigned short Vls[80][80];
  __shared__ float red[4];
  int qt = blockIdx.x, bh = blockIdx.y, b = bh >> 4, h = bh & 15;
  int tid = threadIdx.x, lane = tid & 63, w = tid >> 6;
  int l15 = lane & 15, l4 = lane >> 4;
  zeroKpad(Ks, tid);
  for (int idx = tid; idx < 80; idx += 256) {   // zero V pad rows 72..79
    int r = 72 + idx / 10, c = idx % 10;
    *(short8*)&Vhs[r][c * 8] = (short8)0;
    *(short8*)&Vls[r][c * 8] = (short8)0;
  }
  int qrow = qt * 64 + w * 16 + l15;
  int qc = qrow > Sd - 1 ? Sd - 1 : qrow;
  short8 q0, q1, q2;
  loadQ(Qq, b, h, qc, l4, q0, q1, q2);
  float s16 = qscale(slots[SL_LOGIT], 32767.f);
  float sqk = qscale(slots[SL_Q], 127.f) * qscale(slots[SL_K], 127.f);
  float c0 = sqk / s16;
  float c1e = s16 * SCALE_F * LOG2E;
  float pmaxv = 1.0f / slots[SL_LMIN];
  float sp = fmaxf(pmaxv, 1e-8f) / 32767.0f;
  float inv_sp = 1.0f / sp;
  float mn_l = m_arr[bh * Sd + qc];               // n-space row max
  float c2 = (1.0f / l_arr[bh * Sd + qc]) * inv_sp;
  f32x4 acc[5];
#pragma unroll
  for (int i = 0; i < 5; ++i) acc[i] = f32x4{0.f, 0.f, 0.f, 0.f};
  long vbase = (long)bh * HDd * VROW;
#pragma unroll 1
  for (int kt = 0; kt < 12; ++kt) {
    __syncthreads();
    stageK(Ks, Kq, b, h, kt * 64, tid);
    for (int idx = tid; idx < 72 * 8; idx += 256) {
      int d = idx >> 3, c = idx & 7;
      long off = vbase + (long)d * VROW + kt * 64 + c * 8;
      *(short8*)&Vhs[d][c * 8] = *(const short8*)&Vh[off];
      *(short8*)&Vls[d][c * 8] = *(const short8*)&Vl[off];
    }
    __syncthreads();
#pragma unroll
    for (int cf = 0; cf < 4; ++cf) {
      const unsigned short* kp = &Ks[cf * 16 + l15][l4 * 8];
      f32x4 a = f32x4{0.f, 0.f, 0.f, 0.f};
      a = MFMA32(*(const short8*)&kp[0],  q0, a);
      a = MFMA32(*(const short8*)&kp[32], q1, a);
      a = MFMA32(*(const short8*)&kp[64], q2, a);
      // P for q=l15, k=cf*16+l4*4+j : quantize + exact bf16 split, in-register
      unsigned phb[4], rsb[4];
#pragma unroll
      for (int j = 0; j < 4; ++j) {
        float n = rintf(a[j] * c0);
        float e = fexp2((n - mn_l) * c1e);
        float nn = rintf(e * c2);                       // [0, 32767]
        unsigned ub = __float_as_uint(nn);
        unsigned ph = (ub + 0x7FFFu + ((ub >> 16) & 1u)) >> 16;   // bf16 RNE
        float rsf = nn - __uint_as_float(ph << 16);     // exact residual, exact bf16
        phb[j] = ph;
        rsb[j] = __float_as_uint(rsf) >> 16;
      }
      short4v Pp = pack4(phb[0], phb[1], phb[2], phb[3]);
      short4v Pr = pack4(rsb[0], rsb[1], rsb[2], rsb[3]);
#pragma unroll
      for (int dt = 0; dt < 5; ++dt) {
        short4v vh = *(const short4v*)&Vhs[dt * 16 + l15][cf * 16 + l4 * 4];
        short4v vl = *(const short4v*)&Vls[dt * 16 + l15][cf * 16 + l4 * 4];
        acc[dt] = MFMA16(Pp, vh, acc[dt]);
        acc[dt] = MFMA16(Pp, vl, acc[dt]);
        acc[dt] = MFMA16(Pr, vh, acc[dt]);   // res@vl dropped (rel err ~2^-23)
      }
    }
  }
  float lmax = 0.f;
#pragma unroll
  for (int dt = 0; dt < 5; ++dt) {
    int d = dt * 16 + l15;
#pragma unroll
    for (int j = 0; j < 4; ++j) {
      int qr = qt * 64 + w * 16 + l4 * 4 + j;
      if (qr < Sd && d < HDd) {
        float v = sp * acc[dt][j];
        O[((long)(b * Sd + qr)) * Hdim + h * HDd + d] = v;
        lmax = fmaxf(lmax, fabsf(v));
      }
    }
  }
  for (int off = 32; off; off >>= 1) lmax = fmaxf(lmax, __shfl_xor(lmax, off, 64));
  if ((tid & 63) == 0) red[w] = lmax;
  __syncthreads();
  if (tid == 0)
    atomicMaxF(&slots[SL_O], fmaxf(fmaxf(red[0], red[1]), fmaxf(red[2], red[3])));
}

// ---------------- host ----------------
extern "C" void kernel_launch(void* const* d_in, const int* in_sizes, int n_in,
                              void* d_out, int out_size, void* d_ws, size_t ws_size,
                              hipStream_t stream) {
  const float* Xin = (const float*)d_in[0];
  const float* Wq = (const float*)d_in[1];
  const float* bq = (const float*)d_in[2];
  const float* Wk = (const float*)d_in[3];
  const float* bk = (const float*)d_in[4];
  const float* Wv = (const float*)d_in[5];
  const float* bv = (const float*)d_in[6];
  const float* Wo = (const float*)d_in[7];
  const float* bo = (const float*)d_in[8];
  float* out = (float*)d_out;
  char* ws = (char*)d_ws;

  size_t off = 0;
  auto alloc = [&](size_t bytes) {
    void* p = ws + off;
    off = (off + bytes + 255) & ~(size_t)255;
    return p;
  };
  float* slots = (float*)alloc(256);
  unsigned short* Xq  = (unsigned short*)alloc((size_t)Ntok * Hdim * 2);
  unsigned short* Wqq = (unsigned short*)alloc((size_t)Hdim * Hdim * 2);
  unsigned short* Wkq = (unsigned short*)alloc((size_t)Hdim * Hdim * 2);
  unsigned short* Wvq = (unsigned short*)alloc((size_t)Hdim * Hdim * 2);
  unsigned short* Woq = (unsigned short*)alloc((size_t)Hdim * Hdim * 2);
  float* Kf = (float*)alloc((size_t)Ntok * Hdim * 4);
  float* Vf = (float*)alloc((size_t)Ntok * Hdim * 4);
  unsigned short* Qq = (unsigned short*)alloc((size_t)Ntok * Hdim * 2);
  unsigned short* Kq = (unsigned short*)alloc((size_t)Ntok * Hdim * 2);
  unsigned short* Vth = (unsigned short*)alloc((size_t)BHd * HDd * VROW * 2);
  unsigned short* Vtl = (unsigned short*)alloc((size_t)BHd * HDd * VROW * 2);
  float* m_arr = (float*)alloc((size_t)BHd * Sd * 4);
  float* l_arr = (float*)alloc((size_t)BHd * Sd * 4);
  // aliases (lifetimes disjoint): Qf32 in d_out; O f32 over Kf; Oq over Vf
  float* Qf = out;
  float* Of = Kf;
  unsigned short* Oq = (unsigned short*)Vf;

  k_init<<<1, 64, 0, stream>>>(slots);
  k_absmax<<<dim3(256, 5), 256, 0, stream>>>(Xin, Wq, Wk, Wv, Wo, slots);
  k_quant8<<<1024, 256, 0, stream>>>(Xin, Xq, (long)Ntok * Hdim, slots, SL_X);
  k_quant8w<<<dim3(128, 4), 256, 0, stream>>>(Wq, Wk, Wv, Wo, Wqq, Wkq, Wvq, Woq, slots);

  dim3 ggrid(92, 9);
  k_gemm<<<ggrid, 256, 0, stream>>>(Xq, Wqq, bq, Qf, slots, SL_X, SL_WQ, SL_Q);
  k_gemm<<<ggrid, 256, 0, stream>>>(Xq, Wkq, bk, Kf, slots, SL_X, SL_WK, SL_K);
  k_gemm<<<ggrid, 256, 0, stream>>>(Xq, Wvq, bv, Vf, slots, SL_X, SL_WV, SL_V);

  k_quant8<<<1024, 256, 0, stream>>>(Qf, Qq, (long)Ntok * Hdim, slots, SL_Q);
  k_quant8<<<1024, 256, 0, stream>>>(Kf, Kq, (long)Ntok * Hdim, slots, SL_K);
  k_vsplit<<<dim3(6, 256), 256, 0, stream>>>(Vf, Vth, Vtl);

  dim3 agrid(12, 256);
  k_attnA<<<agrid, 256, 0, stream>>>(Qq, Kq, slots);
  k_attnB<<<agrid, 256, 0, stream>>>(Qq, Kq, slots, m_arr, l_arr);
  k_attnC<<<agrid, 256, 0, stream>>>(Qq, Kq, Vth, Vtl, m_arr, l_arr, slots, Of);

  k_quant8<<<1024, 256, 0, stream>>>(Of, Oq, (long)Ntok * Hdim, slots, SL_O);
  k_gemm<<<ggrid, 256, 0, stream>>>(Oq, Woq, bo, out, slots, SL_O, SL_WO, -1);
}

// Round 3
// 730.840 us; speedup vs baseline: 1.8500x; 1.1588x over previous
//
#include <hip/hip_runtime.h>
#include <math.h>

// Problem constants
#define Hdim 1152
#define NHd  16
#define HDd  72
#define Bd   16
#define Sd   729
#define Ntok (Bd*Sd)      // 11664
#define BHd  (Bd*NHd)     // 256
#define SCALE_F 0.117851130197757934f  // 72^-0.5
#define LOG2E 1.44269504088896340736f

// Fragment-tile sizes (ushorts)
#define KFT 6144    // per (bh,kt): 12 chunks * 512
#define VFT 10240   // per (bh,kt): 40 chunks * 256

// scalar slots in ws
#define SL_X 0
#define SL_WQ 1
#define SL_WK 2
#define SL_WV 3
#define SL_WO 4
#define SL_Q 5
#define SL_K 6
#define SL_LOGIT 8
#define SL_LMIN 9
#define SL_O 10

typedef short short8 __attribute__((ext_vector_type(8)));
typedef short short4v __attribute__((ext_vector_type(4)));
typedef float f32x4 __attribute__((ext_vector_type(4)));

static __device__ __forceinline__ unsigned short f2bf(float f) {
  unsigned b = __float_as_uint(f);
  return (unsigned short)((b + 0x7FFFu + ((b >> 16) & 1u)) >> 16);  // RNE
}
static __device__ __forceinline__ float bf2f(unsigned short u) {
  return __uint_as_float(((unsigned)u) << 16);
}
static __device__ __forceinline__ void atomicMaxF(float* p, float v) {
  atomicMax((unsigned int*)p, __float_as_uint(v));   // v >= 0 only
}
static __device__ __forceinline__ void atomicMinF(float* p, float v) {
  atomicMin((unsigned int*)p, __float_as_uint(v));   // v > 0 only
}
static __device__ __forceinline__ float qscale(float mx, float qmax) {
  return fmaxf(mx, 1e-8f) / qmax;
}
static __device__ __forceinline__ float fexp2(float x) {
  float r; asm("v_exp_f32 %0, %1" : "=v"(r) : "v"(x)); return r;
}
static __device__ __forceinline__ short4v pack4(unsigned a, unsigned b, unsigned c, unsigned d) {
  union { unsigned u[2]; short4v s; } t;
  t.u[0] = a | (b << 16);
  t.u[1] = c | (d << 16);
  return t.s;
}

#define MFMA32(a, b, c) __builtin_amdgcn_mfma_f32_16x16x32_bf16(a, b, c, 0, 0, 0)
#if __has_builtin(__builtin_amdgcn_mfma_f32_16x16x16bf16_1k)
#define MFMA16(a, b, c) __builtin_amdgcn_mfma_f32_16x16x16bf16_1k(a, b, c, 0, 0, 0)
#else
static __device__ __forceinline__ f32x4 MFMA16(short4v a, short4v b, f32x4 c) {
  asm("v_mfma_f32_16x16x16_bf16 %0, %1, %2, %0" : "+v"(c) : "v"(a), "v"(b));
  return c;
}
#endif

static __device__ __forceinline__ void gll16(const void* g, void* l) {
  __builtin_amdgcn_global_load_lds((const __attribute__((address_space(1))) void*)g,
                                   (__attribute__((address_space(3))) void*)l, 16, 0, 0);
}

// XCD-grouped (qt,bh) ids: all 12 qt-blocks of one bh land on one XCD
static __device__ __forceinline__ void attn_ids(int& qt, int& bh) {
  int id = blockIdx.y * 12 + blockIdx.x;   // 0..3071
  int xcd = id & 7, sub = id >> 3;         // 384 per xcd
  int bhl = sub / 12;
  qt = sub - bhl * 12;
  bh = xcd * 32 + bhl;
}

// ---------------- init ----------------
__global__ void k_init(float* slots) {
  int i = threadIdx.x;
  if (i < 32) slots[i] = (i == SL_LMIN) ? __builtin_inff() : 0.0f;
}

// ---------------- abs-max over X and the 4 weights ----------------
__launch_bounds__(256)
__global__ void k_absmax(const float* __restrict__ X, const float* __restrict__ W0,
                         const float* __restrict__ W1, const float* __restrict__ W2,
                         const float* __restrict__ W3, float* slots) {
  int seg = blockIdx.y;
  const float* p; long n; int slot;
  if (seg == 0) { p = X; n = (long)Ntok * Hdim; slot = SL_X; }
  else {
    const float* ws4[4] = {W0, W1, W2, W3};
    p = ws4[seg - 1]; n = (long)Hdim * Hdim; slot = SL_WQ + seg - 1;
  }
  long n4 = n >> 2;
  const float4* p4 = (const float4*)p;
  float m = 0.f;
  for (long i = (long)blockIdx.x * blockDim.x + threadIdx.x; i < n4;
       i += (long)gridDim.x * blockDim.x) {
    float4 v = p4[i];
    m = fmaxf(m, fmaxf(fmaxf(fabsf(v.x), fabsf(v.y)), fmaxf(fabsf(v.z), fabsf(v.w))));
  }
  for (int off = 32; off; off >>= 1) m = fmaxf(m, __shfl_xor(m, off, 64));
  __shared__ float red[4];
  if ((threadIdx.x & 63) == 0) red[threadIdx.x >> 6] = m;
  __syncthreads();
  if (threadIdx.x == 0)
    atomicMaxF(&slots[slot], fmaxf(fmaxf(red[0], red[1]), fmaxf(red[2], red[3])));
}

// ---------------- 8-bit fake-quant: f32 -> integer-valued bf16 ----------------
__launch_bounds__(256)
__global__ void k_quant8(const float* __restrict__ in, unsigned short* __restrict__ out,
                         long n, const float* __restrict__ slots, int slot) {
  float s = qscale(slots[slot], 127.0f);
  long n4 = n >> 2;
  const float4* in4 = (const float4*)in;
  ushort4* out4 = (ushort4*)out;
  for (long i = (long)blockIdx.x * blockDim.x + threadIdx.x; i < n4;
       i += (long)gridDim.x * blockDim.x) {
    float4 v = in4[i];
    ushort4 o;
    o.x = f2bf(fminf(fmaxf(rintf(v.x / s), -128.f), 127.f));
    o.y = f2bf(fminf(fmaxf(rintf(v.y / s), -128.f), 127.f));
    o.z = f2bf(fminf(fmaxf(rintf(v.z / s), -128.f), 127.f));
    o.w = f2bf(fminf(fmaxf(rintf(v.w / s), -128.f), 127.f));
    out4[i] = o;
  }
}

// combined 4-weight quant
__launch_bounds__(256)
__global__ void k_quant8w(const float* __restrict__ W0, const float* __restrict__ W1,
                          const float* __restrict__ W2, const float* __restrict__ W3,
                          unsigned short* O0, unsigned short* O1,
                          unsigned short* O2, unsigned short* O3,
                          const float* __restrict__ slots) {
  int seg = blockIdx.y;
  const float* ws4[4] = {W0, W1, W2, W3};
  unsigned short* os4[4] = {O0, O1, O2, O3};
  const float* in = ws4[seg];
  unsigned short* out = os4[seg];
  float s = qscale(slots[SL_WQ + seg], 127.0f);
  long n4 = ((long)Hdim * Hdim) >> 2;
  const float4* in4 = (const float4*)in;
  ushort4* out4 = (ushort4*)out;
  for (long i = (long)blockIdx.x * blockDim.x + threadIdx.x; i < n4;
       i += (long)gridDim.x * blockDim.x) {
    float4 v = in4[i];
    ushort4 o;
    o.x = f2bf(fminf(fmaxf(rintf(v.x / s), -128.f), 127.f));
    o.y = f2bf(fminf(fmaxf(rintf(v.y / s), -128.f), 127.f));
    o.z = f2bf(fminf(fmaxf(rintf(v.z / s), -128.f), 127.f));
    o.w = f2bf(fminf(fmaxf(rintf(v.w / s), -128.f), 127.f));
    out4[i] = o;
  }
}

// ---------------- GEMM (m97 structure): C = alpha*(A@B^T) + bias ----------------
#define GBM 128
#define GBN 128
#define GBK 32
__launch_bounds__(256, 3)
__global__ void k_gemm(const unsigned short* __restrict__ A,
                       const unsigned short* __restrict__ Bm,
                       const float* __restrict__ bias,
                       float* __restrict__ C,
                       float* slots, int slotA, int slotB, int slotOut) {
  __shared__ unsigned short As[GBM][GBK];
  __shared__ unsigned short Bs[GBN][GBK];
  __shared__ float red[4];
  int tid = threadIdx.x, lane = tid & 63, wid = tid >> 6;
  int wm = wid >> 1, wn = wid & 1;
  int l15 = lane & 15, l4 = lane >> 4;
  int bM = blockIdx.x, bN = blockIdx.y;
  f32x4 acc[4][4];
  for (int rf = 0; rf < 4; ++rf)
    for (int cf = 0; cf < 4; ++cf) acc[rf][cf] = f32x4{0.f, 0.f, 0.f, 0.f};

  int srow = lane >> 2, scol = (lane & 3) * 8;
  const unsigned short* pa = A + ((long)(bM * GBM + wid * 32) + srow) * Hdim + scol;
  const unsigned short* pb = Bm + ((long)(bN * GBN + wid * 32) + srow) * Hdim + scol;

  for (int kt = 0; kt < Hdim / GBK; ++kt) {
    int kb = kt * GBK;
    __syncthreads();
    gll16(pa + kb, &As[wid * 32][0]);
    gll16(pa + kb + 16 * Hdim, &As[wid * 32 + 16][0]);
    gll16(pb + kb, &Bs[wid * 32][0]);
    gll16(pb + kb + 16 * Hdim, &Bs[wid * 32 + 16][0]);
    __syncthreads();
    short8 af[4], bf[4];
#pragma unroll
    for (int rf = 0; rf < 4; ++rf) af[rf] = *(const short8*)&As[wm * 64 + rf * 16 + l15][l4 * 8];
#pragma unroll
    for (int cf = 0; cf < 4; ++cf) bf[cf] = *(const short8*)&Bs[wn * 64 + cf * 16 + l15][l4 * 8];
#pragma unroll
    for (int rf = 0; rf < 4; ++rf)
#pragma unroll
      for (int cf = 0; cf < 4; ++cf)
        acc[rf][cf] = MFMA32(af[rf], bf[cf], acc[rf][cf]);
  }
  float alpha = qscale(slots[slotA], 127.f) * qscale(slots[slotB], 127.f);
  float lmax = 0.f;
#pragma unroll
  for (int cf = 0; cf < 4; ++cf) {
    int col = bN * GBN + wn * 64 + cf * 16 + l15;
    float bv = bias[col];
#pragma unroll
    for (int rf = 0; rf < 4; ++rf)
#pragma unroll
      for (int j = 0; j < 4; ++j) {
        int row = bM * GBM + wm * 64 + rf * 16 + l4 * 4 + j;
        if (row < Ntok) {
          float v = acc[rf][cf][j] * alpha + bv;
          C[(long)row * Hdim + col] = v;
          lmax = fmaxf(lmax, fabsf(v));
        }
      }
  }
  if (slotOut >= 0) {
    for (int off = 32; off; off >>= 1) lmax = fmaxf(lmax, __shfl_xor(lmax, off, 64));
    if ((tid & 63) == 0) red[wid] = lmax;
    __syncthreads();
    if (tid == 0)
      atomicMaxF(&slots[slotOut], fmaxf(fmaxf(red[0], red[1]), fmaxf(red[2], red[3])));
  }
}

// ---------------- K f32 -> fragment-major quantized bf16 ----------------
// Kfrag[bh][kt][p=cf*3+c][lane][8] ; value K[token=kt*64+cf*16+l15][d=c*32+l4*8+i]
__launch_bounds__(256)
__global__ void k_kfrag(const float* __restrict__ Kf, unsigned short* __restrict__ KF,
                        const float* __restrict__ slots, int bh0) {
  int kt = blockIdx.x, bh = bh0 + blockIdx.y;
  int b = bh >> 4, h = bh & 15;
  float s = qscale(slots[SL_K], 127.0f);
  int tid = threadIdx.x, lane = tid & 63, w = tid >> 6;
  int l15 = lane & 15, l4 = lane >> 4;
  long obase = ((long)(bh * 12 + kt)) * KFT;
#pragma unroll
  for (int i = 0; i < 3; ++i) {
    int p = w + 4 * i;
    int cf = p / 3, c = p - cf * 3;
    int token = kt * 64 + cf * 16 + l15;
    int d0 = c * 32 + l4 * 8;
    unsigned short ov[8];
    if (token < Sd && d0 < HDd) {
      const float* src = &Kf[((long)(b * Sd + token)) * Hdim + h * HDd + d0];
#pragma unroll
      for (int j = 0; j < 8; ++j)
        ov[j] = f2bf(fminf(fmaxf(rintf(src[j] / s), -128.f), 127.f));
    } else {
#pragma unroll
      for (int j = 0; j < 8; ++j) ov[j] = 0;
    }
    *(short8*)&KF[obase + (long)p * 512 + lane * 8] = *(short8*)ov;
  }
}

// ---------------- V f32 -> fragment-major hi/lo bf16 ----------------
// Vfrag[bh][kt][p=dt*4+cf][a][lane][4] ; value V[token=kt*64+cf*16+l4*4+i][d=dt*16+l15]
__launch_bounds__(256)
__global__ void k_vsplit(const float* __restrict__ Vf, unsigned short* __restrict__ VF) {
  int kt = blockIdx.x, bh = blockIdx.y;
  int b = bh >> 4, h = bh & 15;
  int tid = threadIdx.x, lane = tid & 63, w = tid >> 6;
  int l15 = lane & 15, l4 = lane >> 4;
  long obase = ((long)(bh * 12 + kt)) * VFT;
#pragma unroll
  for (int i = 0; i < 5; ++i) {
    int p = w + 4 * i;            // p = dt*4 + cf
    int dt = p >> 2, cf = p & 3;
    int d = dt * 16 + l15;
    int tok0 = kt * 64 + cf * 16 + l4 * 4;
    unsigned short hp[4], lp[4];
#pragma unroll
    for (int j = 0; j < 4; ++j) {
      int tok = tok0 + j;
      float v = 0.f;
      if (tok < Sd && d < HDd)
        v = Vf[((long)(b * Sd + tok)) * Hdim + h * HDd + d];
      unsigned short hb = f2bf(v);
      hp[j] = hb;
      lp[j] = f2bf(v - bf2f(hb));
    }
    *(ushort4*)&VF[obase + (long)(p * 2 + 0) * 256 + lane * 4] = *(ushort4*)hp;
    *(ushort4*)&VF[obase + (long)(p * 2 + 1) * 256 + lane * 4] = *(ushort4*)lp;
  }
}

// per-lane Q fragments straight from global (B-operand: q col = l15, d = chunk*32+l4*8+i)
static __device__ __forceinline__ void loadQ(const unsigned short* __restrict__ Qq,
                                             int b, int h, int qc, int l4,
                                             short8& q0, short8& q1, short8& q2) {
  const unsigned short* qp = &Qq[((long)(b * Sd + qc)) * Hdim + h * HDd];
  q0 = *(const short8*)&qp[l4 * 8];
  q1 = *(const short8*)&qp[32 + l4 * 8];
  q2 = (short8)0;
  if (l4 == 0) q2 = *(const short8*)&qp[64];
}

// stage one K fragment tile (12 KB) into LDS, linear
static __device__ __forceinline__ void stageKf(unsigned short* lds,
                                               const unsigned short* g, int w, int lane) {
#pragma unroll
  for (int i = 0; i < 3; ++i) {
    int c = w + 4 * i;
    gll16(g + c * 512 + lane * 8, lds + c * 512);
  }
}
// stage one V fragment tile (20 KB) into LDS, linear
static __device__ __forceinline__ void stageVf(unsigned short* lds,
                                               const unsigned short* g, int w, int lane) {
#pragma unroll
  for (int i = 0; i < 5; ++i) {
    int c = w + 4 * i;
    gll16(g + c * 512 + lane * 8, lds + c * 512);
  }
}

// ---------------- attn pass A: global max |logit| ----------------
__launch_bounds__(256, 4)
__global__ void k_attnA(const unsigned short* __restrict__ Qq,
                        const unsigned short* __restrict__ KF, float* slots) {
  __shared__ unsigned short Ks[KFT];
  __shared__ float red[4];
  int qt, bh; attn_ids(qt, bh);
  int b = bh >> 4, h = bh & 15;
  int tid = threadIdx.x, lane = tid & 63, w = tid >> 6;
  int l15 = lane & 15, l4 = lane >> 4;
  int qrow = qt * 64 + w * 16 + l15;
  int qc = qrow > Sd - 1 ? Sd - 1 : qrow;
  short8 q0, q1, q2;
  loadQ(Qq, b, h, qc, l4, q0, q1, q2);
  const unsigned short* kfb = KF + (long)bh * 12 * KFT;
  float mx = 0.f;
#pragma unroll 1
  for (int kt = 0; kt < 12; ++kt) {
    __syncthreads();
    stageKf(Ks, kfb + kt * KFT, w, lane);
    __syncthreads();
#pragma unroll
    for (int cf = 0; cf < 4; ++cf) {
      f32x4 a = f32x4{0.f, 0.f, 0.f, 0.f};
      a = MFMA32(*(const short8*)&Ks[(cf * 3 + 0) * 512 + lane * 8], q0, a);
      a = MFMA32(*(const short8*)&Ks[(cf * 3 + 1) * 512 + lane * 8], q1, a);
      a = MFMA32(*(const short8*)&Ks[(cf * 3 + 2) * 512 + lane * 8], q2, a);
      mx = fmaxf(mx, fmaxf(fmaxf(fabsf(a[0]), fabsf(a[1])), fmaxf(fabsf(a[2]), fabsf(a[3]))));
    }
  }
  mx *= qscale(slots[SL_Q], 127.f) * qscale(slots[SL_K], 127.f);
  for (int off = 32; off; off >>= 1) mx = fmaxf(mx, __shfl_xor(mx, off, 64));
  if ((tid & 63) == 0) red[w] = mx;
  __syncthreads();
  if (tid == 0)
    atomicMaxF(&slots[SL_LOGIT], fmaxf(fmaxf(red[0], red[1]), fmaxf(red[2], red[3])));
}

// ---------------- attn pass B: per-row m (n-space), l ; global min l ----------------
__launch_bounds__(256, 4)
__global__ void k_attnB(const unsigned short* __restrict__ Qq,
                        const unsigned short* __restrict__ KF, float* slots,
                        float* __restrict__ m_arr, float* __restrict__ l_arr) {
  __shared__ unsigned short Ks[KFT];
  __shared__ float red[4];
  int qt, bh; attn_ids(qt, bh);
  int b = bh >> 4, h = bh & 15;
  int tid = threadIdx.x, lane = tid & 63, w = tid >> 6;
  int l15 = lane & 15, l4 = lane >> 4;
  int qrow = qt * 64 + w * 16 + l15;
  int qc = qrow > Sd - 1 ? Sd - 1 : qrow;
  short8 q0, q1, q2;
  loadQ(Qq, b, h, qc, l4, q0, q1, q2);
  const unsigned short* kfb = KF + (long)bh * 12 * KFT;
  float s16 = qscale(slots[SL_LOGIT], 32767.f);
  float sqk = qscale(slots[SL_Q], 127.f) * qscale(slots[SL_K], 127.f);
  float c0 = sqk / s16;                 // raw-dot -> n units
  float c1e = s16 * SCALE_F * LOG2E;    // n units -> log2 space
  float m_run = -3.0e38f, l_run = 0.f;
#pragma unroll 1
  for (int kt = 0; kt < 12; ++kt) {
    __syncthreads();
    stageKf(Ks, kfb + kt * KFT, w, lane);
    __syncthreads();
    float nv[16];
#pragma unroll
    for (int cf = 0; cf < 4; ++cf) {
      f32x4 a = f32x4{0.f, 0.f, 0.f, 0.f};
      a = MFMA32(*(const short8*)&Ks[(cf * 3 + 0) * 512 + lane * 8], q0, a);
      a = MFMA32(*(const short8*)&Ks[(cf * 3 + 1) * 512 + lane * 8], q1, a);
      a = MFMA32(*(const short8*)&Ks[(cf * 3 + 2) * 512 + lane * 8], q2, a);
#pragma unroll
      for (int j = 0; j < 4; ++j) nv[cf * 4 + j] = rintf(a[j] * c0);
    }
    if (kt == 11) {
#pragma unroll
      for (int cf = 0; cf < 4; ++cf)
#pragma unroll
        for (int j = 0; j < 4; ++j) {
          int kcol = 704 + cf * 16 + l4 * 4 + j;
          if (kcol > Sd - 1) nv[cf * 4 + j] = -3.0e30f;
        }
    }
    float mt = nv[0];
#pragma unroll
    for (int i = 1; i < 16; ++i) mt = fmaxf(mt, nv[i]);
    mt = fmaxf(mt, __shfl_xor(mt, 16, 64));
    mt = fmaxf(mt, __shfl_xor(mt, 32, 64));
    float mn = fmaxf(m_run, mt);
    float f = fexp2((m_run - mn) * c1e);
    float se = 0.f;
#pragma unroll
    for (int i = 0; i < 16; ++i) se += fexp2((nv[i] - mn) * c1e);
    se += __shfl_xor(se, 16, 64);
    se += __shfl_xor(se, 32, 64);
    l_run = l_run * f + se;
    m_run = mn;
  }
  if (l4 == 0 && qrow < Sd) {
    m_arr[bh * Sd + qrow] = m_run;      // n-space max
    l_arr[bh * Sd + qrow] = l_run;
  }
  float lmin = (qrow < Sd) ? l_run : 3.0e38f;
  for (int off = 32; off; off >>= 1) lmin = fminf(lmin, __shfl_xor(lmin, off, 64));
  if ((tid & 63) == 0) red[w] = lmin;
  __syncthreads();
  if (tid == 0)
    atomicMinF(&slots[SL_LMIN], fminf(fminf(red[0], red[1]), fminf(red[2], red[3])));
}

// ---------------- attn pass C: register-P quant + P@V + max|O| ----------------
__launch_bounds__(256, 4)
__global__ void k_attnC(const unsigned short* __restrict__ Qq,
                        const unsigned short* __restrict__ KF,
                        const unsigned short* __restrict__ VF,
                        const float* __restrict__ m_arr, const float* __restrict__ l_arr,
                        float* slots, float* __restrict__ O) {
  __shared__ unsigned short Ks[KFT];
  __shared__ unsigned short Vs[VFT];
  __shared__ float red[4];
  int qt, bh; attn_ids(qt, bh);
  int b = bh >> 4, h = bh & 15;
  int tid = threadIdx.x, lane = tid & 63, w = tid >> 6;
  int l15 = lane & 15, l4 = lane >> 4;
  int qrow = qt * 64 + w * 16 + l15;
  int qc = qrow > Sd - 1 ? Sd - 1 : qrow;
  short8 q0, q1, q2;
  loadQ(Qq, b, h, qc, l4, q0, q1, q2);
  const unsigned short* kfb = KF + (long)bh * 12 * KFT;
  const unsigned short* vfb = VF + (long)bh * 12 * VFT;
  float s16 = qscale(slots[SL_LOGIT], 32767.f);
  float sqk = qscale(slots[SL_Q], 127.f) * qscale(slots[SL_K], 127.f);
  float c0 = sqk / s16;
  float c1e = s16 * SCALE_F * LOG2E;
  float pmaxv = 1.0f / slots[SL_LMIN];
  float sp = fmaxf(pmaxv, 1e-8f) / 32767.0f;
  float inv_sp = 1.0f / sp;
  float mn_l = m_arr[bh * Sd + qc];               // n-space row max
  float c2 = (1.0f / l_arr[bh * Sd + qc]) * inv_sp;
  f32x4 acc[5];
#pragma unroll
  for (int i = 0; i < 5; ++i) acc[i] = f32x4{0.f, 0.f, 0.f, 0.f};
#pragma unroll 1
  for (int kt = 0; kt < 12; ++kt) {
    __syncthreads();
    stageKf(Ks, kfb + kt * KFT, w, lane);
    stageVf(Vs, vfb + kt * VFT, w, lane);
    __syncthreads();
#pragma unroll
    for (int cf = 0; cf < 4; ++cf) {
      f32x4 a = f32x4{0.f, 0.f, 0.f, 0.f};
      a = MFMA32(*(const short8*)&Ks[(cf * 3 + 0) * 512 + lane * 8], q0, a);
      a = MFMA32(*(const short8*)&Ks[(cf * 3 + 1) * 512 + lane * 8], q1, a);
      a = MFMA32(*(const short8*)&Ks[(cf * 3 + 2) * 512 + lane * 8], q2, a);
      // P for q=l15, k=cf*16+l4*4+j : quantize + exact bf16 split, in-register
      unsigned phb[4], rsb[4];
#pragma unroll
      for (int j = 0; j < 4; ++j) {
        float n = rintf(a[j] * c0);
        float e = fexp2((n - mn_l) * c1e);
        float nn = rintf(e * c2);                       // [0, 32767]
        unsigned ub = __float_as_uint(nn);
        unsigned ph = (ub + 0x7FFFu + ((ub >> 16) & 1u)) >> 16;   // bf16 RNE
        float rsf = nn - __uint_as_float(ph << 16);     // exact residual, exact bf16
        phb[j] = ph;
        rsb[j] = __float_as_uint(rsf) >> 16;
      }
      short4v Pp = pack4(phb[0], phb[1], phb[2], phb[3]);
      short4v Pr = pack4(rsb[0], rsb[1], rsb[2], rsb[3]);
#pragma unroll
      for (int dt = 0; dt < 5; ++dt) {
        int base = ((dt * 4 + cf) * 2) * 256 + lane * 4;
        short4v vh = *(const short4v*)&Vs[base];
        short4v vl = *(const short4v*)&Vs[base + 256];
        acc[dt] = MFMA16(Pp, vh, acc[dt]);
        acc[dt] = MFMA16(Pp, vl, acc[dt]);
        acc[dt] = MFMA16(Pr, vh, acc[dt]);   // res@vl dropped (rel err ~2^-23)
      }
    }
  }
  float lmax = 0.f;
#pragma unroll
  for (int dt = 0; dt < 5; ++dt) {
    int d = dt * 16 + l15;
#pragma unroll
    for (int j = 0; j < 4; ++j) {
      int qr = qt * 64 + w * 16 + l4 * 4 + j;
      if (qr < Sd && d < HDd) {
        float v = sp * acc[dt][j];
        O[((long)(b * Sd + qr)) * Hdim + h * HDd + d] = v;
        lmax = fmaxf(lmax, fabsf(v));
      }
    }
  }
  for (int off = 32; off; off >>= 1) lmax = fmaxf(lmax, __shfl_xor(lmax, off, 64));
  if ((tid & 63) == 0) red[w] = lmax;
  __syncthreads();
  if (tid == 0)
    atomicMaxF(&slots[SL_O], fmaxf(fmaxf(red[0], red[1]), fmaxf(red[2], red[3])));
}

// ---------------- host ----------------
extern "C" void kernel_launch(void* const* d_in, const int* in_sizes, int n_in,
                              void* d_out, int out_size, void* d_ws, size_t ws_size,
                              hipStream_t stream) {
  const float* Xin = (const float*)d_in[0];
  const float* Wq = (const float*)d_in[1];
  const float* bq = (const float*)d_in[2];
  const float* Wk = (const float*)d_in[3];
  const float* bk = (const float*)d_in[4];
  const float* Wv = (const float*)d_in[5];
  const float* bv = (const float*)d_in[6];
  const float* Wo = (const float*)d_in[7];
  const float* bo = (const float*)d_in[8];
  float* out = (float*)d_out;
  char* ws = (char*)d_ws;

  size_t off = 0;
  auto alloc = [&](size_t bytes) {
    void* p = ws + off;
    off = (off + bytes + 255) & ~(size_t)255;
    return p;
  };
  float* slots = (float*)alloc(256);
  unsigned short* Woq = (unsigned short*)alloc((size_t)Hdim * Hdim * 2);
  unsigned short* Xq  = (unsigned short*)alloc((size_t)Ntok * Hdim * 2);
  unsigned short* Wqq = (unsigned short*)alloc((size_t)Hdim * Hdim * 2);
  unsigned short* Wkq = (unsigned short*)alloc((size_t)Hdim * Hdim * 2);
  unsigned short* Wvq = (unsigned short*)alloc((size_t)Hdim * Hdim * 2);
  float* Kf = (float*)alloc((size_t)Ntok * Hdim * 4);
  float* Vf = (float*)alloc((size_t)Ntok * Hdim * 4);
  unsigned short* Qq = (unsigned short*)alloc((size_t)Ntok * Hdim * 2);
  unsigned short* VFr = (unsigned short*)alloc((size_t)BHd * 12 * VFT * 2);
  float* m_arr = (float*)alloc((size_t)BHd * Sd * 4);
  float* l_arr = (float*)alloc((size_t)BHd * Sd * 4);
  // Aliases (lifetimes disjoint):
  //  Kfrag (37.75 MB) over Xq+Wqq+Wkq+Wvq (34.84 MB) + first 2.91 MB of Kf
  //    -> safe via 2-phase k_kfrag: phase1 (bh<16) reads Kf b=0 before phase2
  //       overwrites Kf head while reading only b>=1.
  //  Q f32 and O f32 live in d_out (Qq extracted before attnC overwrites).
  //  Oq over Vf (dead after k_vsplit).
  unsigned short* KFr = Xq;
  unsigned short* Oq = (unsigned short*)Vf;
  float* Qf = out;
  float* Of = out;

  k_init<<<1, 64, 0, stream>>>(slots);
  k_absmax<<<dim3(256, 5), 256, 0, stream>>>(Xin, Wq, Wk, Wv, Wo, slots);
  k_quant8<<<1024, 256, 0, stream>>>(Xin, Xq, (long)Ntok * Hdim, slots, SL_X);
  k_quant8w<<<dim3(128, 4), 256, 0, stream>>>(Wq, Wk, Wv, Wo, Wqq, Wkq, Wvq, Woq, slots);

  dim3 ggrid(92, 9);
  k_gemm<<<ggrid, 256, 0, stream>>>(Xq, Wqq, bq, Qf, slots, SL_X, SL_WQ, SL_Q);
  k_gemm<<<ggrid, 256, 0, stream>>>(Xq, Wkq, bk, Kf, slots, SL_X, SL_WK, SL_K);
  k_gemm<<<ggrid, 256, 0, stream>>>(Xq, Wvq, bv, Vf, slots, SL_X, SL_WV, -1);

  k_quant8<<<1024, 256, 0, stream>>>(Qf, Qq, (long)Ntok * Hdim, slots, SL_Q);
  k_kfrag<<<dim3(12, 16), 256, 0, stream>>>(Kf, KFr, slots, 0);    // b=0 (Kf head)
  k_kfrag<<<dim3(12, 240), 256, 0, stream>>>(Kf, KFr, slots, 16);  // b>=1
  k_vsplit<<<dim3(12, 256), 256, 0, stream>>>(Vf, VFr);

  dim3 agrid(12, 256);
  k_attnA<<<agrid, 256, 0, stream>>>(Qq, KFr, slots);
  k_attnB<<<agrid, 256, 0, stream>>>(Qq, KFr, slots, m_arr, l_arr);
  k_attnC<<<agrid, 256, 0, stream>>>(Qq, KFr, VFr, m_arr, l_arr, slots, Of);

  k_quant8<<<1024, 256, 0, stream>>>(Of, Oq, (long)Ntok * Hdim, slots, SL_O);
  k_gemm<<<ggrid, 256, 0, stream>>>(Oq, Woq, bo, out, slots, SL_O, SL_WO, -1);
}

// Round 4
// 692.869 us; speedup vs baseline: 1.9513x; 1.0548x over previous
//
#include <hip/hip_runtime.h>
#include <math.h>

// Problem constants
#define Hdim 1152
#define NHd  16
#define HDd  72
#define Bd   16
#define Sd   729
#define Ntok (Bd*Sd)      // 11664
#define BHd  (Bd*NHd)     // 256
#define SCALE_F 0.117851130197757934f  // 72^-0.5
#define LOG2E 1.44269504088896340736f

// Fragment-tile sizes (ushorts)
#define KFT 6144    // per (bh,kt): 12 chunks * 512
#define VFT 10240   // per (bh,kt): 40 chunks * 256

// scalar slots in ws
#define SL_X 0
#define SL_WQ 1
#define SL_WK 2
#define SL_WV 3
#define SL_WO 4
#define SL_Q 5
#define SL_K 6
#define SL_LOGIT 8
#define SL_LMIN 9
#define SL_O 10

typedef short short8 __attribute__((ext_vector_type(8)));
typedef short short4v __attribute__((ext_vector_type(4)));
typedef float f32x4 __attribute__((ext_vector_type(4)));

static __device__ __forceinline__ unsigned short f2bf(float f) {
  unsigned b = __float_as_uint(f);
  return (unsigned short)((b + 0x7FFFu + ((b >> 16) & 1u)) >> 16);  // RNE
}
static __device__ __forceinline__ float bf2f(unsigned short u) {
  return __uint_as_float(((unsigned)u) << 16);
}
static __device__ __forceinline__ void atomicMaxF(float* p, float v) {
  atomicMax((unsigned int*)p, __float_as_uint(v));   // v >= 0 only
}
static __device__ __forceinline__ void atomicMinF(float* p, float v) {
  atomicMin((unsigned int*)p, __float_as_uint(v));   // v > 0 only
}
static __device__ __forceinline__ float qscale(float mx, float qmax) {
  return fmaxf(mx, 1e-8f) / qmax;
}
static __device__ __forceinline__ float fexp2(float x) {
  float r; asm("v_exp_f32 %0, %1" : "=v"(r) : "v"(x)); return r;
}
static __device__ __forceinline__ short4v pack4(unsigned a, unsigned b, unsigned c, unsigned d) {
  union { unsigned u[2]; short4v s; } t;
  t.u[0] = a | (b << 16);
  t.u[1] = c | (d << 16);
  return t.s;
}

#define MFMA32(a, b, c) __builtin_amdgcn_mfma_f32_16x16x32_bf16(a, b, c, 0, 0, 0)
#if __has_builtin(__builtin_amdgcn_mfma_f32_16x16x16bf16_1k)
#define MFMA16(a, b, c) __builtin_amdgcn_mfma_f32_16x16x16bf16_1k(a, b, c, 0, 0, 0)
#else
static __device__ __forceinline__ f32x4 MFMA16(short4v a, short4v b, f32x4 c) {
  asm("v_mfma_f32_16x16x16_bf16 %0, %1, %2, %0" : "+v"(c) : "v"(a), "v"(b));
  return c;
}
#endif

static __device__ __forceinline__ void gll16(const void* g, void* l) {
  __builtin_amdgcn_global_load_lds((const __attribute__((address_space(1))) void*)g,
                                   (__attribute__((address_space(3))) void*)l, 16, 0, 0);
}

// XCD-grouped (qt,bh) ids for attnC: all 12 qt-blocks of one bh land on one XCD
static __device__ __forceinline__ void attn_ids(int& qt, int& bh) {
  int id = blockIdx.y * 12 + blockIdx.x;   // 0..3071
  int xcd = id & 7, sub = id >> 3;         // 384 per xcd
  int bhl = sub / 12;
  qt = sub - bhl * 12;
  bh = xcd * 32 + bhl;
}

// ---------------- init ----------------
__global__ void k_init(float* slots) {
  int i = threadIdx.x;
  if (i < 32) slots[i] = (i == SL_LMIN) ? __builtin_inff() : 0.0f;
}

// ---------------- abs-max over X and the 4 weights ----------------
__launch_bounds__(256)
__global__ void k_absmax(const float* __restrict__ X, const float* __restrict__ W0,
                         const float* __restrict__ W1, const float* __restrict__ W2,
                         const float* __restrict__ W3, float* slots) {
  int seg = blockIdx.y;
  const float* p; long n; int slot;
  if (seg == 0) { p = X; n = (long)Ntok * Hdim; slot = SL_X; }
  else {
    const float* ws4[4] = {W0, W1, W2, W3};
    p = ws4[seg - 1]; n = (long)Hdim * Hdim; slot = SL_WQ + seg - 1;
  }
  long n4 = n >> 2;
  const float4* p4 = (const float4*)p;
  float m = 0.f;
  for (long i = (long)blockIdx.x * blockDim.x + threadIdx.x; i < n4;
       i += (long)gridDim.x * blockDim.x) {
    float4 v = p4[i];
    m = fmaxf(m, fmaxf(fmaxf(fabsf(v.x), fabsf(v.y)), fmaxf(fabsf(v.z), fabsf(v.w))));
  }
  for (int off = 32; off; off >>= 1) m = fmaxf(m, __shfl_xor(m, off, 64));
  __shared__ float red[4];
  if ((threadIdx.x & 63) == 0) red[threadIdx.x >> 6] = m;
  __syncthreads();
  if (threadIdx.x == 0)
    atomicMaxF(&slots[slot], fmaxf(fmaxf(red[0], red[1]), fmaxf(red[2], red[3])));
}

// ---------------- 8-bit fake-quant: f32 -> integer-valued bf16 ----------------
__launch_bounds__(256)
__global__ void k_quant8(const float* __restrict__ in, unsigned short* __restrict__ out,
                         long n, const float* __restrict__ slots, int slot) {
  float s = qscale(slots[slot], 127.0f);
  long n4 = n >> 2;
  const float4* in4 = (const float4*)in;
  ushort4* out4 = (ushort4*)out;
  for (long i = (long)blockIdx.x * blockDim.x + threadIdx.x; i < n4;
       i += (long)gridDim.x * blockDim.x) {
    float4 v = in4[i];
    ushort4 o;
    o.x = f2bf(fminf(fmaxf(rintf(v.x / s), -128.f), 127.f));
    o.y = f2bf(fminf(fmaxf(rintf(v.y / s), -128.f), 127.f));
    o.z = f2bf(fminf(fmaxf(rintf(v.z / s), -128.f), 127.f));
    o.w = f2bf(fminf(fmaxf(rintf(v.w / s), -128.f), 127.f));
    out4[i] = o;
  }
}

// combined 4-weight quant
__launch_bounds__(256)
__global__ void k_quant8w(const float* __restrict__ W0, const float* __restrict__ W1,
                          const float* __restrict__ W2, const float* __restrict__ W3,
                          unsigned short* O0, unsigned short* O1,
                          unsigned short* O2, unsigned short* O3,
                          const float* __restrict__ slots) {
  int seg = blockIdx.y;
  const float* ws4[4] = {W0, W1, W2, W3};
  unsigned short* os4[4] = {O0, O1, O2, O3};
  const float* in = ws4[seg];
  unsigned short* out = os4[seg];
  float s = qscale(slots[SL_WQ + seg], 127.0f);
  long n4 = ((long)Hdim * Hdim) >> 2;
  const float4* in4 = (const float4*)in;
  ushort4* out4 = (ushort4*)out;
  for (long i = (long)blockIdx.x * blockDim.x + threadIdx.x; i < n4;
       i += (long)gridDim.x * blockDim.x) {
    float4 v = in4[i];
    ushort4 o;
    o.x = f2bf(fminf(fmaxf(rintf(v.x / s), -128.f), 127.f));
    o.y = f2bf(fminf(fmaxf(rintf(v.y / s), -128.f), 127.f));
    o.z = f2bf(fminf(fmaxf(rintf(v.z / s), -128.f), 127.f));
    o.w = f2bf(fminf(fmaxf(rintf(v.w / s), -128.f), 127.f));
    out4[i] = o;
  }
}

// ---------------- GEMM (m97 structure): C = alpha*(A@B^T) + bias ----------------
#define GBM 128
#define GBN 128
#define GBK 32
__launch_bounds__(256, 3)
__global__ void k_gemm(const unsigned short* __restrict__ A,
                       const unsigned short* __restrict__ Bm,
                       const float* __restrict__ bias,
                       float* __restrict__ C,
                       float* slots, int slotA, int slotB, int slotOut) {
  __shared__ unsigned short As[GBM][GBK];
  __shared__ unsigned short Bs[GBN][GBK];
  __shared__ float red[4];
  int tid = threadIdx.x, lane = tid & 63, wid = tid >> 6;
  int wm = wid >> 1, wn = wid & 1;
  int l15 = lane & 15, l4 = lane >> 4;
  int bM = blockIdx.x, bN = blockIdx.y;
  f32x4 acc[4][4];
  for (int rf = 0; rf < 4; ++rf)
    for (int cf = 0; cf < 4; ++cf) acc[rf][cf] = f32x4{0.f, 0.f, 0.f, 0.f};

  int srow = lane >> 2, scol = (lane & 3) * 8;
  const unsigned short* pa = A + ((long)(bM * GBM + wid * 32) + srow) * Hdim + scol;
  const unsigned short* pb = Bm + ((long)(bN * GBN + wid * 32) + srow) * Hdim + scol;

  for (int kt = 0; kt < Hdim / GBK; ++kt) {
    int kb = kt * GBK;
    __syncthreads();
    gll16(pa + kb, &As[wid * 32][0]);
    gll16(pa + kb + 16 * Hdim, &As[wid * 32 + 16][0]);
    gll16(pb + kb, &Bs[wid * 32][0]);
    gll16(pb + kb + 16 * Hdim, &Bs[wid * 32 + 16][0]);
    __syncthreads();
    short8 af[4], bf[4];
#pragma unroll
    for (int rf = 0; rf < 4; ++rf) af[rf] = *(const short8*)&As[wm * 64 + rf * 16 + l15][l4 * 8];
#pragma unroll
    for (int cf = 0; cf < 4; ++cf) bf[cf] = *(const short8*)&Bs[wn * 64 + cf * 16 + l15][l4 * 8];
#pragma unroll
    for (int rf = 0; rf < 4; ++rf)
#pragma unroll
      for (int cf = 0; cf < 4; ++cf)
        acc[rf][cf] = MFMA32(af[rf], bf[cf], acc[rf][cf]);
  }
  float alpha = qscale(slots[slotA], 127.f) * qscale(slots[slotB], 127.f);
  float lmax = 0.f;
#pragma unroll
  for (int cf = 0; cf < 4; ++cf) {
    int col = bN * GBN + wn * 64 + cf * 16 + l15;
    float bv = bias[col];
#pragma unroll
    for (int rf = 0; rf < 4; ++rf)
#pragma unroll
      for (int j = 0; j < 4; ++j) {
        int row = bM * GBM + wm * 64 + rf * 16 + l4 * 4 + j;
        if (row < Ntok) {
          float v = acc[rf][cf][j] * alpha + bv;
          C[(long)row * Hdim + col] = v;
          lmax = fmaxf(lmax, fabsf(v));
        }
      }
  }
  if (slotOut >= 0) {
    for (int off = 32; off; off >>= 1) lmax = fmaxf(lmax, __shfl_xor(lmax, off, 64));
    if ((tid & 63) == 0) red[wid] = lmax;
    __syncthreads();
    if (tid == 0)
      atomicMaxF(&slots[slotOut], fmaxf(fmaxf(red[0], red[1]), fmaxf(red[2], red[3])));
  }
}

// ---------------- K f32 -> fragment-major quantized bf16 ----------------
// Kfrag[bh][kt][p=cf*3+c][lane][8] ; value K[token=kt*64+cf*16+l15][d=c*32+l4*8+i]
__launch_bounds__(256)
__global__ void k_kfrag(const float* __restrict__ Kf, unsigned short* __restrict__ KF,
                        const float* __restrict__ slots, int bh0) {
  int kt = blockIdx.x, bh = bh0 + blockIdx.y;
  int b = bh >> 4, h = bh & 15;
  float s = qscale(slots[SL_K], 127.0f);
  int tid = threadIdx.x, lane = tid & 63, w = tid >> 6;
  int l15 = lane & 15, l4 = lane >> 4;
  long obase = ((long)(bh * 12 + kt)) * KFT;
#pragma unroll
  for (int i = 0; i < 3; ++i) {
    int p = w + 4 * i;
    int cf = p / 3, c = p - cf * 3;
    int token = kt * 64 + cf * 16 + l15;
    int d0 = c * 32 + l4 * 8;
    unsigned short ov[8];
    if (token < Sd && d0 < HDd) {
      const float* src = &Kf[((long)(b * Sd + token)) * Hdim + h * HDd + d0];
#pragma unroll
      for (int j = 0; j < 8; ++j)
        ov[j] = f2bf(fminf(fmaxf(rintf(src[j] / s), -128.f), 127.f));
    } else {
#pragma unroll
      for (int j = 0; j < 8; ++j) ov[j] = 0;
    }
    *(short8*)&KF[obase + (long)p * 512 + lane * 8] = *(short8*)ov;
  }
}

// ---------------- V f32 -> fragment-major hi/lo bf16 ----------------
// Vfrag[bh][kt][p=dt*4+cf][a][lane][4] ; value V[token=kt*64+cf*16+l4*4+i][d=dt*16+l15]
__launch_bounds__(256)
__global__ void k_vsplit(const float* __restrict__ Vf, unsigned short* __restrict__ VF) {
  int kt = blockIdx.x, bh = blockIdx.y;
  int b = bh >> 4, h = bh & 15;
  int tid = threadIdx.x, lane = tid & 63, w = tid >> 6;
  int l15 = lane & 15, l4 = lane >> 4;
  long obase = ((long)(bh * 12 + kt)) * VFT;
#pragma unroll
  for (int i = 0; i < 5; ++i) {
    int p = w + 4 * i;            // p = dt*4 + cf
    int dt = p >> 2, cf = p & 3;
    int d = dt * 16 + l15;
    int tok0 = kt * 64 + cf * 16 + l4 * 4;
    unsigned short hp[4], lp[4];
#pragma unroll
    for (int j = 0; j < 4; ++j) {
      int tok = tok0 + j;
      float v = 0.f;
      if (tok < Sd && d < HDd)
        v = Vf[((long)(b * Sd + tok)) * Hdim + h * HDd + d];
      unsigned short hb = f2bf(v);
      hp[j] = hb;
      lp[j] = f2bf(v - bf2f(hb));
    }
    *(ushort4*)&VF[obase + (long)(p * 2 + 0) * 256 + lane * 4] = *(ushort4*)hp;
    *(ushort4*)&VF[obase + (long)(p * 2 + 1) * 256 + lane * 4] = *(ushort4*)lp;
  }
}

// per-lane Q fragments straight from global (B-operand: q col = l15, d = chunk*32+l4*8+i)
static __device__ __forceinline__ void loadQ(const unsigned short* __restrict__ Qq,
                                             int b, int h, int qc, int l4,
                                             short8& q0, short8& q1, short8& q2) {
  const unsigned short* qp = &Qq[((long)(b * Sd + qc)) * Hdim + h * HDd];
  q0 = *(const short8*)&qp[l4 * 8];
  q1 = *(const short8*)&qp[32 + l4 * 8];
  q2 = (short8)0;
  if (l4 == 0) q2 = *(const short8*)&qp[64];
}

// ---------------- attn pass A: global max |logit| ----------------
// grid (4, 256): block = (qh, bh), 3 q-tiles each. K frags in registers, no LDS/barriers.
__launch_bounds__(256, 3)
__global__ void k_attnA(const unsigned short* __restrict__ Qq,
                        const unsigned short* __restrict__ KF, float* slots) {
  __shared__ float red[4];
  int qh = blockIdx.x, bh = blockIdx.y;
  int b = bh >> 4, h = bh & 15;
  int tid = threadIdx.x, lane = tid & 63, w = tid >> 6;
  int l15 = lane & 15, l4 = lane >> 4;
  const unsigned short* kfb = KF + (long)bh * 12 * KFT;
  float mx = 0.f;
#pragma unroll 1
  for (int kt = 0; kt < 12; ++kt) {
    short8 kf[12];
#pragma unroll
    for (int p = 0; p < 12; ++p)
      kf[p] = *(const short8*)&kfb[(long)kt * KFT + p * 512 + lane * 8];
#pragma unroll
    for (int qs = 0; qs < 3; ++qs) {
      int qt = qh * 3 + qs;
      int qrow = qt * 64 + w * 16 + l15;
      int qc = qrow > Sd - 1 ? Sd - 1 : qrow;
      short8 q0, q1, q2;
      loadQ(Qq, b, h, qc, l4, q0, q1, q2);
#pragma unroll
      for (int cf = 0; cf < 4; ++cf) {
        f32x4 a = f32x4{0.f, 0.f, 0.f, 0.f};
        a = MFMA32(kf[cf * 3 + 0], q0, a);
        a = MFMA32(kf[cf * 3 + 1], q1, a);
        a = MFMA32(kf[cf * 3 + 2], q2, a);
        mx = fmaxf(mx, fmaxf(fmaxf(fabsf(a[0]), fabsf(a[1])), fmaxf(fabsf(a[2]), fabsf(a[3]))));
      }
    }
  }
  mx *= qscale(slots[SL_Q], 127.f) * qscale(slots[SL_K], 127.f);
  for (int off = 32; off; off >>= 1) mx = fmaxf(mx, __shfl_xor(mx, off, 64));
  if ((tid & 63) == 0) red[w] = mx;
  __syncthreads();
  if (tid == 0)
    atomicMaxF(&slots[SL_LOGIT], fmaxf(fmaxf(red[0], red[1]), fmaxf(red[2], red[3])));
}

// ---------------- attn pass B: per-row m (n-space), l ; global min l ----------------
// grid (4, 256): same register-K structure, per-qt running state in registers.
__launch_bounds__(256, 3)
__global__ void k_attnB(const unsigned short* __restrict__ Qq,
                        const unsigned short* __restrict__ KF, float* slots,
                        float* __restrict__ m_arr, float* __restrict__ l_arr) {
  __shared__ float red[4];
  int qh = blockIdx.x, bh = blockIdx.y;
  int b = bh >> 4, h = bh & 15;
  int tid = threadIdx.x, lane = tid & 63, w = tid >> 6;
  int l15 = lane & 15, l4 = lane >> 4;
  const unsigned short* kfb = KF + (long)bh * 12 * KFT;
  float s16 = qscale(slots[SL_LOGIT], 32767.f);
  float sqk = qscale(slots[SL_Q], 127.f) * qscale(slots[SL_K], 127.f);
  float c0 = sqk / s16;                 // raw-dot -> n units
  float c1e = s16 * SCALE_F * LOG2E;    // n units -> log2 space
  float m_run[3] = {-3.0e38f, -3.0e38f, -3.0e38f};
  float l_run[3] = {0.f, 0.f, 0.f};
#pragma unroll 1
  for (int kt = 0; kt < 12; ++kt) {
    short8 kf[12];
#pragma unroll
    for (int p = 0; p < 12; ++p)
      kf[p] = *(const short8*)&kfb[(long)kt * KFT + p * 512 + lane * 8];
#pragma unroll
    for (int qs = 0; qs < 3; ++qs) {
      int qt = qh * 3 + qs;
      int qrow = qt * 64 + w * 16 + l15;
      int qc = qrow > Sd - 1 ? Sd - 1 : qrow;
      short8 q0, q1, q2;
      loadQ(Qq, b, h, qc, l4, q0, q1, q2);
      float nv[16];
#pragma unroll
      for (int cf = 0; cf < 4; ++cf) {
        f32x4 a = f32x4{0.f, 0.f, 0.f, 0.f};
        a = MFMA32(kf[cf * 3 + 0], q0, a);
        a = MFMA32(kf[cf * 3 + 1], q1, a);
        a = MFMA32(kf[cf * 3 + 2], q2, a);
#pragma unroll
        for (int j = 0; j < 4; ++j) nv[cf * 4 + j] = rintf(a[j] * c0);
      }
      if (kt == 11) {
#pragma unroll
        for (int cf = 0; cf < 4; ++cf)
#pragma unroll
          for (int j = 0; j < 4; ++j) {
            int kcol = 704 + cf * 16 + l4 * 4 + j;
            if (kcol > Sd - 1) nv[cf * 4 + j] = -3.0e30f;
          }
      }
      float mt = nv[0];
#pragma unroll
      for (int i = 1; i < 16; ++i) mt = fmaxf(mt, nv[i]);
      mt = fmaxf(mt, __shfl_xor(mt, 16, 64));
      mt = fmaxf(mt, __shfl_xor(mt, 32, 64));
      float mn = fmaxf(m_run[qs], mt);
      float f = fexp2((m_run[qs] - mn) * c1e);
      float se = 0.f;
#pragma unroll
      for (int i = 0; i < 16; ++i) se += fexp2((nv[i] - mn) * c1e);
      se += __shfl_xor(se, 16, 64);
      se += __shfl_xor(se, 32, 64);
      l_run[qs] = l_run[qs] * f + se;
      m_run[qs] = mn;
    }
  }
  float lmin = 3.0e38f;
#pragma unroll
  for (int qs = 0; qs < 3; ++qs) {
    int qrow = (qh * 3 + qs) * 64 + w * 16 + l15;
    if (qrow < Sd) {
      if (l4 == 0) {
        m_arr[bh * Sd + qrow] = m_run[qs];
        l_arr[bh * Sd + qrow] = l_run[qs];
      }
      lmin = fminf(lmin, l_run[qs]);
    }
  }
  for (int off = 32; off; off >>= 1) lmin = fminf(lmin, __shfl_xor(lmin, off, 64));
  if ((tid & 63) == 0) red[w] = lmin;
  __syncthreads();
  if (tid == 0)
    atomicMinF(&slots[SL_LMIN], fminf(fminf(red[0], red[1]), fminf(red[2], red[3])));
}

// ---------------- attn pass C: dbuf LDS + counted vmcnt + register-P + P@V ----------------
__launch_bounds__(256, 2)
__global__ void k_attnC(const unsigned short* __restrict__ Qq,
                        const unsigned short* __restrict__ KF,
                        const unsigned short* __restrict__ VF,
                        const float* __restrict__ m_arr, const float* __restrict__ l_arr,
                        float* slots, float* __restrict__ O) {
  __shared__ unsigned short Ks[2][KFT];
  __shared__ unsigned short Vs[2][VFT];
  __shared__ float red[4];
  int qt, bh; attn_ids(qt, bh);
  int b = bh >> 4, h = bh & 15;
  int tid = threadIdx.x, lane = tid & 63, w = tid >> 6;
  int l15 = lane & 15, l4 = lane >> 4;
  int qrow = qt * 64 + w * 16 + l15;
  int qc = qrow > Sd - 1 ? Sd - 1 : qrow;
  short8 q0, q1, q2;
  loadQ(Qq, b, h, qc, l4, q0, q1, q2);
  const unsigned short* kfb = KF + (long)bh * 12 * KFT;
  const unsigned short* vfb = VF + (long)bh * 12 * VFT;
  float s16 = qscale(slots[SL_LOGIT], 32767.f);
  float sqk = qscale(slots[SL_Q], 127.f) * qscale(slots[SL_K], 127.f);
  float c0 = sqk / s16;
  float c1e = s16 * SCALE_F * LOG2E;
  float pmaxv = 1.0f / slots[SL_LMIN];
  float sp = fmaxf(pmaxv, 1e-8f) / 32767.0f;
  float inv_sp = 1.0f / sp;
  float mn_l = m_arr[bh * Sd + qc];               // n-space row max
  float c2 = (1.0f / l_arr[bh * Sd + qc]) * inv_sp;
  f32x4 acc[5];
#pragma unroll
  for (int i = 0; i < 5; ++i) acc[i] = f32x4{0.f, 0.f, 0.f, 0.f};

  // stage kt's K (3 glls) + V (5 glls) into buffer bufi — 8 VMEM ops per wave
  auto stageKV = [&](int bufi, int kt) {
    const unsigned short* kg = kfb + (long)kt * KFT;
#pragma unroll
    for (int i = 0; i < 3; ++i) {
      int c = w + 4 * i;
      gll16(kg + c * 512 + lane * 8, &Ks[bufi][c * 512]);
    }
    const unsigned short* vg = vfb + (long)kt * VFT;
#pragma unroll
    for (int i = 0; i < 5; ++i) {
      int c = w + 4 * i;
      gll16(vg + c * 512 + lane * 8, &Vs[bufi][c * 512]);
    }
  };

  stageKV(0, 0);
#pragma unroll 1
  for (int kt = 0; kt < 12; ++kt) {
    int cur = kt & 1;
    if (kt < 11) {
      stageKV(cur ^ 1, kt + 1);
      asm volatile("s_waitcnt vmcnt(8)" ::: "memory");   // kt's 8 glls done; kt+1's in flight
    } else {
      asm volatile("s_waitcnt vmcnt(0)" ::: "memory");
    }
    asm volatile("s_barrier" ::: "memory");
#pragma unroll
    for (int cf = 0; cf < 4; ++cf) {
      f32x4 a = f32x4{0.f, 0.f, 0.f, 0.f};
      a = MFMA32(*(const short8*)&Ks[cur][(cf * 3 + 0) * 512 + lane * 8], q0, a);
      a = MFMA32(*(const short8*)&Ks[cur][(cf * 3 + 1) * 512 + lane * 8], q1, a);
      a = MFMA32(*(const short8*)&Ks[cur][(cf * 3 + 2) * 512 + lane * 8], q2, a);
      // P for q=l15, k=cf*16+l4*4+j : quantize + exact bf16 split, in-register
      unsigned phb[4], rsb[4];
#pragma unroll
      for (int j = 0; j < 4; ++j) {
        float n = rintf(a[j] * c0);
        float e = fexp2((n - mn_l) * c1e);
        float nn = rintf(e * c2);                       // [0, 32767]
        unsigned ub = __float_as_uint(nn);
        unsigned ph = (ub + 0x7FFFu + ((ub >> 16) & 1u)) >> 16;   // bf16 RNE
        float rsf = nn - __uint_as_float(ph << 16);     // exact residual, exact bf16
        phb[j] = ph;
        rsb[j] = __float_as_uint(rsf) >> 16;
      }
      short4v Pp = pack4(phb[0], phb[1], phb[2], phb[3]);
      short4v Pr = pack4(rsb[0], rsb[1], rsb[2], rsb[3]);
#pragma unroll
      for (int dt = 0; dt < 5; ++dt) {
        int base = ((dt * 4 + cf) * 2) * 256 + lane * 4;
        short4v vh = *(const short4v*)&Vs[cur][base];
        short4v vl = *(const short4v*)&Vs[cur][base + 256];
        acc[dt] = MFMA16(Pp, vh, acc[dt]);
        acc[dt] = MFMA16(Pp, vl, acc[dt]);
        acc[dt] = MFMA16(Pr, vh, acc[dt]);   // res@vl dropped (rel err ~2^-23)
      }
    }
    asm volatile("s_barrier" ::: "memory");   // reads of buf[cur] done before overwrite
  }
  float lmax = 0.f;
#pragma unroll
  for (int dt = 0; dt < 5; ++dt) {
    int d = dt * 16 + l15;
#pragma unroll
    for (int j = 0; j < 4; ++j) {
      int qr = qt * 64 + w * 16 + l4 * 4 + j;
      if (qr < Sd && d < HDd) {
        float v = sp * acc[dt][j];
        O[((long)(b * Sd + qr)) * Hdim + h * HDd + d] = v;
        lmax = fmaxf(lmax, fabsf(v));
      }
    }
  }
  for (int off = 32; off; off >>= 1) lmax = fmaxf(lmax, __shfl_xor(lmax, off, 64));
  if ((tid & 63) == 0) red[w] = lmax;
  __syncthreads();
  if (tid == 0)
    atomicMaxF(&slots[SL_O], fmaxf(fmaxf(red[0], red[1]), fmaxf(red[2], red[3])));
}

// ---------------- host ----------------
extern "C" void kernel_launch(void* const* d_in, const int* in_sizes, int n_in,
                              void* d_out, int out_size, void* d_ws, size_t ws_size,
                              hipStream_t stream) {
  const float* Xin = (const float*)d_in[0];
  const float* Wq = (const float*)d_in[1];
  const float* bq = (const float*)d_in[2];
  const float* Wk = (const float*)d_in[3];
  const float* bk = (const float*)d_in[4];
  const float* Wv = (const float*)d_in[5];
  const float* bv = (const float*)d_in[6];
  const float* Wo = (const float*)d_in[7];
  const float* bo = (const float*)d_in[8];
  float* out = (float*)d_out;
  char* ws = (char*)d_ws;

  size_t off = 0;
  auto alloc = [&](size_t bytes) {
    void* p = ws + off;
    off = (off + bytes + 255) & ~(size_t)255;
    return p;
  };
  float* slots = (float*)alloc(256);
  unsigned short* Woq = (unsigned short*)alloc((size_t)Hdim * Hdim * 2);
  unsigned short* Xq  = (unsigned short*)alloc((size_t)Ntok * Hdim * 2);
  unsigned short* Wqq = (unsigned short*)alloc((size_t)Hdim * Hdim * 2);
  unsigned short* Wkq = (unsigned short*)alloc((size_t)Hdim * Hdim * 2);
  unsigned short* Wvq = (unsigned short*)alloc((size_t)Hdim * Hdim * 2);
  float* Kf = (float*)alloc((size_t)Ntok * Hdim * 4);
  float* Vf = (float*)alloc((size_t)Ntok * Hdim * 4);
  unsigned short* Qq = (unsigned short*)alloc((size_t)Ntok * Hdim * 2);
  unsigned short* VFr = (unsigned short*)alloc((size_t)BHd * 12 * VFT * 2);
  float* m_arr = (float*)alloc((size_t)BHd * Sd * 4);
  float* l_arr = (float*)alloc((size_t)BHd * Sd * 4);
  // Aliases (lifetimes disjoint):
  //  Kfrag (37.75 MB) over Xq+Wqq+Wkq+Wvq (34.84 MB) + first 2.91 MB of Kf
  //    -> safe via 2-phase k_kfrag: phase1 (bh<16) reads Kf b=0 before phase2
  //       overwrites Kf head while reading only b>=1.
  //  Q f32 and O f32 live in d_out (Qq extracted before attnC overwrites).
  //  Oq over Vf (dead after k_vsplit).
  unsigned short* KFr = Xq;
  unsigned short* Oq = (unsigned short*)Vf;
  float* Qf = out;
  float* Of = out;

  k_init<<<1, 64, 0, stream>>>(slots);
  k_absmax<<<dim3(256, 5), 256, 0, stream>>>(Xin, Wq, Wk, Wv, Wo, slots);
  k_quant8<<<1024, 256, 0, stream>>>(Xin, Xq, (long)Ntok * Hdim, slots, SL_X);
  k_quant8w<<<dim3(128, 4), 256, 0, stream>>>(Wq, Wk, Wv, Wo, Wqq, Wkq, Wvq, Woq, slots);

  dim3 ggrid(92, 9);
  k_gemm<<<ggrid, 256, 0, stream>>>(Xq, Wqq, bq, Qf, slots, SL_X, SL_WQ, SL_Q);
  k_gemm<<<ggrid, 256, 0, stream>>>(Xq, Wkq, bk, Kf, slots, SL_X, SL_WK, SL_K);
  k_gemm<<<ggrid, 256, 0, stream>>>(Xq, Wvq, bv, Vf, slots, SL_X, SL_WV, -1);

  k_quant8<<<1024, 256, 0, stream>>>(Qf, Qq, (long)Ntok * Hdim, slots, SL_Q);
  k_kfrag<<<dim3(12, 16), 256, 0, stream>>>(Kf, KFr, slots, 0);    // b=0 (Kf head)
  k_kfrag<<<dim3(12, 240), 256, 0, stream>>>(Kf, KFr, slots, 16);  // b>=1
  k_vsplit<<<dim3(12, 256), 256, 0, stream>>>(Vf, VFr);

  k_attnA<<<dim3(4, 256), 256, 0, stream>>>(Qq, KFr, slots);
  k_attnB<<<dim3(4, 256), 256, 0, stream>>>(Qq, KFr, slots, m_arr, l_arr);
  k_attnC<<<dim3(12, 256), 256, 0, stream>>>(Qq, KFr, VFr, m_arr, l_arr, slots, Of);

  k_quant8<<<1024, 256, 0, stream>>>(Of, Oq, (long)Ntok * Hdim, slots, SL_O);
  k_gemm<<<ggrid, 256, 0, stream>>>(Oq, Woq, bo, out, slots, SL_O, SL_WO, -1);
}